// Round 1
// baseline (4301.528 us; speedup 1.0000x reference)
//
#include <hip/hip_runtime.h>
#include <hip/hip_bf16.h>
#include <math.h>

// Problem constants (AutoCorrelationAttention): B=8, L=4096, E=1024, H=16, D=64
#define B_ 8
#define L_ 4096
#define E_ 1024
#define H_ 16
#define D_ 64

// ---------------------------------------------------------------------------
// Complex helpers + in-LDS Stockham radix-4 FFT, N=4096 (6 stages), 256 thr.
// sign = -1: forward DFT (matches jnp.fft.rfft convention)
// sign = +1: unnormalized inverse (scale by 1/N outside)
// Result ends up in buffer A (6 stages -> even number of ping-pongs).
// ---------------------------------------------------------------------------
__device__ __forceinline__ float2 cmulf(float2 a, float2 b) {
  return make_float2(a.x * b.x - a.y * b.y, a.x * b.y + a.y * b.x);
}

__device__ void fft4096_r4(float2* __restrict__ A, float2* __restrict__ Bb,
                           int tid, float sign) {
  float2* cur = A;
  float2* nxt = Bb;
  const float TWO_PI = 6.28318530717958647692f;
  for (int Ns = 1; Ns < 4096; Ns *= 4) {
    __syncthreads();
    for (int j = tid; j < 1024; j += 256) {
      float2 v0 = cur[j];
      float2 v1 = cur[j + 1024];
      float2 v2 = cur[j + 2048];
      float2 v3 = cur[j + 3072];
      int r = j & (Ns - 1);
      float ang = sign * TWO_PI * (float)r / (float)(4 * Ns);
      float s1, c1;
      __sincosf(ang, &s1, &c1);
      float2 w1 = make_float2(c1, s1);
      float2 w2 = cmulf(w1, w1);
      float2 w3 = cmulf(w2, w1);
      v1 = cmulf(v1, w1);
      v2 = cmulf(v2, w2);
      v3 = cmulf(v3, w3);
      float2 t0 = make_float2(v0.x + v2.x, v0.y + v2.y);
      float2 t1 = make_float2(v0.x - v2.x, v0.y - v2.y);
      float2 t2 = make_float2(v1.x + v3.x, v1.y + v3.y);
      float2 t3 = make_float2(v1.x - v3.x, v1.y - v3.y);
      float2 t3i = make_float2(-sign * t3.y, sign * t3.x);  // i*sign*t3
      int idxD = ((j - r) << 2) + r;  // (j/Ns)*4Ns + (j%Ns)
      nxt[idxD]          = make_float2(t0.x + t2.x, t0.y + t2.y);
      nxt[idxD + Ns]     = make_float2(t1.x + t3i.x, t1.y + t3i.y);
      nxt[idxD + 2 * Ns] = make_float2(t0.x - t2.x, t0.y - t2.y);
      nxt[idxD + 3 * Ns] = make_float2(t1.x - t3i.x, t1.y - t3i.y);
    }
    float2* tmp = cur; cur = nxt; nxt = tmp;
  }
  __syncthreads();
}

// ---------------------------------------------------------------------------
// Kernel 1: QKV projection, fp32 tiled GEMM. C = x @ W^T + b.
//   z = 0 -> Q, transposed store to QT (B, E, L)
//   z = 1 -> K, transposed store to KT (B, E, L)
//   z = 2 -> V, natural store (B, L, E)  [into d_out used as scratch]
// Tile 128x128, BK=16, 256 threads, 8x8 microtile (split 4+4 at 64-offset
// to keep LDS float4 reads 2-way-conflict-free).
// ---------------------------------------------------------------------------
#define BM 128
#define BN 128
#define BK 16
#define SA_STRIDE 132   // 16B-aligned row stride for staging tiles
#define CS_STRIDE 133   // transpose buffer stride (bank-conflict friendly)

__global__ __launch_bounds__(256) void qkv_gemm(
    const float* __restrict__ x,
    const float* __restrict__ Wq, const float* __restrict__ bq,
    const float* __restrict__ Wk, const float* __restrict__ bk,
    const float* __restrict__ Wv, const float* __restrict__ bv,
    float* __restrict__ QT, float* __restrict__ KT, float* __restrict__ Vout) {
  __shared__ float smem[128 * CS_STRIDE];  // 68.1 KB, aliased staging/transpose
  float* sA = smem;                        // [BK][SA_STRIDE]
  float* sB = smem + BK * SA_STRIDE;       // [BK][SA_STRIDE]

  const int which = blockIdx.z;
  const float* W    = (which == 0) ? Wq : (which == 1) ? Wk : Wv;
  const float* bias = (which == 0) ? bq : (which == 1) ? bk : bv;

  const int n0 = blockIdx.x * BN;
  const int m0 = blockIdx.y * BM;
  const int tid = threadIdx.x;
  const int tx = tid & 15, ty = tid >> 4;

  float acc[8][8];
  #pragma unroll
  for (int i = 0; i < 8; ++i)
    #pragma unroll
    for (int j = 0; j < 8; ++j) acc[i][j] = 0.f;

  for (int k0 = 0; k0 < E_; k0 += BK) {
    __syncthreads();
    #pragma unroll
    for (int rr = 0; rr < 8; ++rr) {
      int row = (tid >> 4) + rr * 16;
      int kk = tid & 15;
      sA[kk * SA_STRIDE + row] = x[(size_t)(m0 + row) * E_ + k0 + kk];
      sB[kk * SA_STRIDE + row] = W[(size_t)(n0 + row) * E_ + k0 + kk];
    }
    __syncthreads();
    #pragma unroll
    for (int kk = 0; kk < BK; ++kk) {
      float a[8], bb[8];
      *(float4*)&a[0]  = *(const float4*)&sA[kk * SA_STRIDE + ty * 4];
      *(float4*)&a[4]  = *(const float4*)&sA[kk * SA_STRIDE + 64 + ty * 4];
      *(float4*)&bb[0] = *(const float4*)&sB[kk * SA_STRIDE + tx * 4];
      *(float4*)&bb[4] = *(const float4*)&sB[kk * SA_STRIDE + 64 + tx * 4];
      #pragma unroll
      for (int i = 0; i < 8; ++i)
        #pragma unroll
        for (int j = 0; j < 8; ++j)
          acc[i][j] = fmaf(a[i], bb[j], acc[i][j]);
    }
  }

  float bias_r[8];
  #pragma unroll
  for (int jh = 0; jh < 2; ++jh)
    #pragma unroll
    for (int j = 0; j < 4; ++j)
      bias_r[jh * 4 + j] = bias[n0 + jh * 64 + tx * 4 + j];

  if (which == 2) {
    // natural (B, L, E)
    #pragma unroll
    for (int ih = 0; ih < 2; ++ih)
      #pragma unroll
      for (int i = 0; i < 4; ++i) {
        int m = m0 + ih * 64 + ty * 4 + i;
        #pragma unroll
        for (int jh = 0; jh < 2; ++jh) {
          float4 vv = make_float4(acc[ih * 4 + i][jh * 4 + 0] + bias_r[jh * 4 + 0],
                                  acc[ih * 4 + i][jh * 4 + 1] + bias_r[jh * 4 + 1],
                                  acc[ih * 4 + i][jh * 4 + 2] + bias_r[jh * 4 + 2],
                                  acc[ih * 4 + i][jh * 4 + 3] + bias_r[jh * 4 + 3]);
          *(float4*)&Vout[(size_t)m * E_ + n0 + jh * 64 + tx * 4] = vv;
        }
      }
  } else {
    float* outT = (which == 0) ? QT : KT;
    __syncthreads();  // staging tiles dead; reuse smem as transpose buffer
    #pragma unroll
    for (int ih = 0; ih < 2; ++ih)
      #pragma unroll
      for (int i = 0; i < 4; ++i)
        #pragma unroll
        for (int jh = 0; jh < 2; ++jh)
          #pragma unroll
          for (int j = 0; j < 4; ++j)
            smem[(jh * 64 + tx * 4 + j) * CS_STRIDE + ih * 64 + ty * 4 + i] =
                acc[ih * 4 + i][jh * 4 + j] + bias_r[jh * 4 + j];
    __syncthreads();
    const int bidx = m0 >> 12;       // m0 / L_
    const int l0 = m0 & (L_ - 1);
    for (int p = 0; p < 64; ++p) {
      int n = p * 2 + (tid >> 7);
      int l = tid & 127;
      outT[(size_t)(bidx * E_ + n0 + n) * L_ + l0 + l] = smem[n * CS_STRIDE + l];
    }
  }
}

// ---------------------------------------------------------------------------
// Kernel 2: per-(b,h) correlation + softmax + attn@V.  One block per (b,h).
//   - 64 packed FFTs (z = q + i*k), Hermitian split, accumulate
//     S[f] = sum_d Qf*conj(Kf) in LDS
//   - one inverse FFT -> corr[l]; softmax over l; out_pre[d] = sum_l attn*V
// ---------------------------------------------------------------------------
__global__ __launch_bounds__(256) void corr_attn(
    const float* __restrict__ QT, const float* __restrict__ KT,
    const float* __restrict__ V, float* __restrict__ out_flat) {
  __shared__ float2 bufA[L_];          // 32 KB
  __shared__ float2 bufB[L_];          // 32 KB
  __shared__ float2 S[L_ / 2 + 1];     // 16.4 KB
  __shared__ float red[256];

  const int bh = blockIdx.x;
  const int b = bh >> 4, h = bh & (H_ - 1);
  const int tid = threadIdx.x;

  for (int f = tid; f <= L_ / 2; f += 256) S[f] = make_float2(0.f, 0.f);

  const size_t baseQK = (size_t)(b * E_ + h * D_) * L_;

  for (int d = 0; d < D_; ++d) {
    __syncthreads();  // prior-iteration bufA readers done
    const float* q = QT + baseQK + (size_t)d * L_;
    const float* k = KT + baseQK + (size_t)d * L_;
    for (int l = tid; l < L_; l += 256) bufA[l] = make_float2(q[l], k[l]);
    fft4096_r4(bufA, bufB, tid, -1.0f);
    // Hermitian split: Qf = (Z + conj(Z[-f]))/2 ; Kf = (Z - conj(Z[-f]))/(2i)
    for (int f = tid; f <= L_ / 2; f += 256) {
      float2 Zf = bufA[f];
      float2 Zc = bufA[(L_ - f) & (L_ - 1)];
      float ax = Zc.x, ay = -Zc.y;
      float qx = 0.5f * (Zf.x + ax), qy = 0.5f * (Zf.y + ay);
      float ux = Zf.x - ax, uy = Zf.y - ay;
      float kx = 0.5f * uy, ky = -0.5f * ux;
      S[f].x += qx * kx + qy * ky;   // Re(Qf * conj(Kf))
      S[f].y += qy * kx - qx * ky;   // Im(Qf * conj(Kf))
    }
  }
  __syncthreads();
  // full Hermitian spectrum -> inverse FFT -> corr
  for (int f = tid; f < L_; f += 256) {
    float2 v;
    if (f <= L_ / 2) v = S[f];
    else { float2 s2 = S[L_ - f]; v = make_float2(s2.x, -s2.y); }
    bufA[f] = v;
  }
  fft4096_r4(bufA, bufB, tid, 1.0f);

  const float cscale = 1.0f / ((float)L_ * (float)D_);  // 1/N (ifft) * 1/D (mean)
  // softmax over l
  float lmax = -3.0e38f;
  for (int l = tid; l < L_; l += 256) lmax = fmaxf(lmax, bufA[l].x);
  red[tid] = lmax;
  __syncthreads();
  for (int s = 128; s > 0; s >>= 1) {
    if (tid < s) red[tid] = fmaxf(red[tid], red[tid + s]);
    __syncthreads();
  }
  const float gmax = red[0] * cscale;
  __syncthreads();
  float lsum = 0.f;
  for (int l = tid; l < L_; l += 256) {
    float w = __expf(bufA[l].x * cscale - gmax);
    bufA[l].x = w;
    lsum += w;
  }
  red[tid] = lsum;
  __syncthreads();
  for (int s = 128; s > 0; s >>= 1) {
    if (tid < s) red[tid] += red[tid + s];
    __syncthreads();
  }
  const float inv = 1.0f / red[0];
  __syncthreads();

  // out_pre[d] = sum_l attn[l] * V[b,l,h*D+d]; 4 l-groups x 64 d lanes
  const int d = tid & 63, g = tid >> 6;
  const float* vb = V + (size_t)b * L_ * E_ + h * D_ + d;
  float acc = 0.f;
  for (int l = g; l < L_; l += 4) acc = fmaf(bufA[l].x, vb[(size_t)l * E_], acc);
  red[tid] = acc;
  __syncthreads();
  if (g == 0) {
    float t = red[d] + red[64 + d] + red[128 + d] + red[192 + d];
    // flat layout (B, E) with j = d*H + h  (from transpose(0,2,1).reshape)
    out_flat[b * E_ + d * H_ + h] = t * inv;
  }
}

// ---------------------------------------------------------------------------
// Kernel 3: y[b,o] = bo[o] + sum_j flat[b,j] * Wo[o,j]   (8 x 1024 x 1024)
// ---------------------------------------------------------------------------
__global__ __launch_bounds__(256) void final_proj(
    const float* __restrict__ flat, const float* __restrict__ Wo,
    const float* __restrict__ bo, float* __restrict__ y) {
  __shared__ float sf[E_];
  const int b = blockIdx.x;
  for (int j = threadIdx.x; j < E_; j += 256) sf[j] = flat[b * E_ + j];
  __syncthreads();
  for (int o = threadIdx.x; o < E_; o += 256) {
    const float4* wr = (const float4*)(Wo + (size_t)o * E_);
    float s = 0.f;
    #pragma unroll 4
    for (int j4 = 0; j4 < E_ / 4; ++j4) {
      float4 w = wr[j4];
      float4 f = *(const float4*)&sf[j4 * 4];
      s += w.x * f.x + w.y * f.y + w.z * f.z + w.w * f.w;
    }
    y[b * E_ + o] = s + bo[o];
  }
}

// ---------------------------------------------------------------------------
// Kernel 4: broadcast y (B,E) to out (B,L,E), float4 stores.
// ---------------------------------------------------------------------------
__global__ void broadcast_out(const float* __restrict__ y,
                              float4* __restrict__ out4) {
  const size_t total = (size_t)B_ * L_ * (E_ / 4);  // 8 * 2^20
  const float4* y4 = (const float4*)y;
  for (size_t i = (size_t)blockIdx.x * blockDim.x + threadIdx.x; i < total;
       i += (size_t)gridDim.x * blockDim.x) {
    size_t e4 = i & (E_ / 4 - 1);
    size_t b = i >> 20;  // / (L_ * E_/4)
    out4[i] = y4[b * (E_ / 4) + e4];
  }
}

// ---------------------------------------------------------------------------
extern "C" void kernel_launch(void* const* d_in, const int* in_sizes, int n_in,
                              void* d_out, int out_size, void* d_ws,
                              size_t ws_size, hipStream_t stream) {
  const float* x  = (const float*)d_in[0];
  const float* Wq = (const float*)d_in[1];
  const float* bq = (const float*)d_in[2];
  const float* Wk = (const float*)d_in[3];
  const float* bk = (const float*)d_in[4];
  const float* Wv = (const float*)d_in[5];
  const float* bv = (const float*)d_in[6];
  const float* Wo = (const float*)d_in[7];
  const float* bo = (const float*)d_in[8];
  float* out = (float*)d_out;
  float* ws = (float*)d_ws;

  // Workspace layout (floats): QT | KT | flat | y   -> 268.5 MB total
  float* QT   = ws;
  float* KT   = ws + (size_t)33554432;
  float* flat = ws + (size_t)67108864;
  float* y    = ws + (size_t)67117056;
  float* V    = out;  // d_out doubles as V scratch; overwritten by broadcast

  qkv_gemm<<<dim3(E_ / BN, (B_ * L_) / BM, 3), 256, 0, stream>>>(
      x, Wq, bq, Wk, bk, Wv, bv, QT, KT, V);
  corr_attn<<<dim3(B_ * H_), 256, 0, stream>>>(QT, KT, V, flat);
  final_proj<<<dim3(B_), 256, 0, stream>>>(flat, Wo, bo, y);
  broadcast_out<<<dim3(2048), 256, 0, stream>>>(y, (float4*)out);
}

// Round 2
// 1797.896 us; speedup vs baseline: 2.3925x; 2.3925x over previous
//
#include <hip/hip_runtime.h>
#include <hip/hip_bf16.h>
#include <math.h>

// Problem constants (AutoCorrelationAttention): B=8, L=4096, E=1024, H=16, D=64
#define B_ 8
#define L_ 4096
#define E_ 1024
#define H_ 16
#define D_ 64

typedef short short8 __attribute__((ext_vector_type(8)));
typedef float f32x4 __attribute__((ext_vector_type(4)));

__device__ __forceinline__ unsigned short f2bf(float f) {
  unsigned int u = __float_as_uint(f);
  unsigned int r = u + 0x7FFFu + ((u >> 16) & 1u);
  return (unsigned short)(r >> 16);
}
__device__ __forceinline__ float bf2f(unsigned short h) {
  return __uint_as_float(((unsigned int)h) << 16);
}

#define GLDS16(g, l)                                                     \
  __builtin_amdgcn_global_load_lds(                                      \
      (const __attribute__((address_space(1))) void*)(g),                \
      (__attribute__((address_space(3))) void*)(l), 16, 0, 0)

// ---------------------------------------------------------------------------
// Kernel 0: split Wq/Wk/Wv into bf16 hi/lo, fused [3072][1024] layout.
// ---------------------------------------------------------------------------
__global__ __launch_bounds__(256) void conv_w(
    const float* __restrict__ Wq, const float* __restrict__ Wk,
    const float* __restrict__ Wv, unsigned short* __restrict__ Whi,
    unsigned short* __restrict__ Wlo) {
  const int wsel = blockIdx.y;
  const float* W = (wsel == 0) ? Wq : (wsel == 1) ? Wk : Wv;
  size_t i = ((size_t)blockIdx.x * 256 + threadIdx.x) * 4;
  float4 f = *(const float4*)(W + i);
  size_t o = (size_t)wsel * (1024 * 1024) + i;
  ushort4 h, l;
  float ff[4] = {f.x, f.y, f.z, f.w};
  unsigned short hh[4], ll[4];
#pragma unroll
  for (int e = 0; e < 4; ++e) {
    hh[e] = f2bf(ff[e]);
    ll[e] = f2bf(ff[e] - bf2f(hh[e]));
  }
  h = make_ushort4(hh[0], hh[1], hh[2], hh[3]);
  l = make_ushort4(ll[0], ll[1], ll[2], ll[3]);
  *(ushort4*)(Whi + o) = h;
  *(ushort4*)(Wlo + o) = l;
}

// ---------------------------------------------------------------------------
// Kernel 1: fused QKV projection, split-bf16 MFMA GEMM (3-term, fp32-grade).
// C[32768, 3072] = x[32768,1024] @ [Wq;Wk;Wv]^T + bias
// 128x128 tile, BK=64, 256 thr (4 waves, 2x2), per-wave 64x64 (4x4 frags of
// 16x16x32). Per k-chunk: acc += Ahi*Bhi + Alo*Bhi + Ahi*Blo.
// Epilogue: Q,K -> transposed fp32 (B,E,L); V -> natural bf16 (B,L,E).
// ---------------------------------------------------------------------------
__global__ __launch_bounds__(256) void qkv_gemm(
    const float* __restrict__ x, const unsigned short* __restrict__ Whi,
    const unsigned short* __restrict__ Wlo, const float* __restrict__ bq,
    const float* __restrict__ bk, const float* __restrict__ bv,
    float* __restrict__ QT, float* __restrict__ KT,
    unsigned short* __restrict__ Vb) {
  __shared__ unsigned short sAhi[128 * 64];
  __shared__ unsigned short sAlo[128 * 64];
  __shared__ unsigned short sBhi[128 * 64];
  __shared__ unsigned short sBlo[128 * 64];

  const int tid = threadIdx.x;
  const int wid = tid >> 6, lane = tid & 63;
  const int n0 = blockIdx.x * 128;  // 0..2944 (fused N)
  const int m0 = blockIdx.y * 128;

  f32x4 acc[4][4];
#pragma unroll
  for (int i = 0; i < 4; ++i)
#pragma unroll
    for (int j = 0; j < 4; ++j) acc[i][j] = (f32x4){0.f, 0.f, 0.f, 0.f};

  const int brow = lane >> 3;          // B-stage: row within 8-row block
  const int bcol = (lane & 7) * 8;     // B-stage: col (elems)
  const int arow = tid >> 3;           // A-stage: row within 32-row quarter
  const int acol = (tid & 7) * 8;      // A-stage: col (elems)
  const int wm = (wid >> 1) * 64, wn = (wid & 1) * 64;
  const int fr = lane & 15, fg = lane >> 4;  // frag row/col id, k-group

  for (int k0 = 0; k0 < E_; k0 += 64) {
    __syncthreads();
    // ---- stage B hi/lo direct to LDS (16 issues each, 4 per wave)
#pragma unroll
    for (int q = 0; q < 4; ++q) {
      const int rb = (wid * 4 + q) * 8;
      GLDS16(Whi + (size_t)(n0 + rb + brow) * E_ + k0 + bcol, &sBhi[rb * 64]);
      GLDS16(Wlo + (size_t)(n0 + rb + brow) * E_ + k0 + bcol, &sBlo[rb * 64]);
    }
    // ---- stage A: fp32 -> hi/lo bf16, lane-linear ds_write (conflict-free)
#pragma unroll
    for (int q = 0; q < 4; ++q) {
      float af[8];
      const float* g = x + (size_t)(m0 + q * 32 + arow) * E_ + k0 + acol;
      *(float4*)&af[0] = *(const float4*)(g);
      *(float4*)&af[4] = *(const float4*)(g + 4);
      short8 vh, vl;
#pragma unroll
      for (int e = 0; e < 8; ++e) {
        unsigned short h = f2bf(af[e]);
        vh[e] = (short)h;
        vl[e] = (short)f2bf(af[e] - bf2f(h));
      }
      *(short8*)&sAhi[q * 2048 + tid * 8] = vh;
      *(short8*)&sAlo[q * 2048 + tid * 8] = vl;
    }
    __syncthreads();
    // ---- compute: 3 passes x 32 MFMA
#pragma unroll
    for (int p = 0; p < 3; ++p) {
      const unsigned short* ab = (p == 1) ? sAlo : sAhi;
      const unsigned short* bb = (p == 2) ? sBlo : sBhi;
      short8 afr[4][2], bfr[4][2];
#pragma unroll
      for (int i = 0; i < 4; ++i)
#pragma unroll
        for (int kk = 0; kk < 2; ++kk) {
          afr[i][kk] = *(const short8*)&ab[(wm + i * 16 + fr) * 64 + kk * 32 + fg * 8];
          bfr[i][kk] = *(const short8*)&bb[(wn + i * 16 + fr) * 64 + kk * 32 + fg * 8];
        }
#pragma unroll
      for (int i = 0; i < 4; ++i)
#pragma unroll
        for (int j = 0; j < 4; ++j)
#pragma unroll
          for (int kk = 0; kk < 2; ++kk)
            acc[i][j] = __builtin_amdgcn_mfma_f32_16x16x32_bf16(
                afr[i][kk], bfr[j][kk], acc[i][j], 0, 0, 0);
    }
  }

  // ---- epilogue
  const int wsel = n0 >> 10;
  const float* bias = (wsel == 0) ? bq : (wsel == 1) ? bk : bv;
  float br[4];
#pragma unroll
  for (int j = 0; j < 4; ++j)
    br[j] = bias[(n0 & 1023) + wn + j * 16 + fr];

  if (wsel < 2) {
    float* T = (wsel == 0) ? QT : KT;
    const int b = m0 >> 12;
    const int lbase = (m0 & 4095) + wm + (fg << 2);
#pragma unroll
    for (int i = 0; i < 4; ++i)
#pragma unroll
      for (int j = 0; j < 4; ++j) {
        const int n_in = (n0 & 1023) + wn + j * 16 + fr;
        float4 v = make_float4(acc[i][j][0] + br[j], acc[i][j][1] + br[j],
                               acc[i][j][2] + br[j], acc[i][j][3] + br[j]);
        *(float4*)&T[((size_t)(b << 10) + n_in) * L_ + lbase + i * 16] = v;
      }
  } else {
#pragma unroll
    for (int i = 0; i < 4; ++i)
#pragma unroll
      for (int j = 0; j < 4; ++j) {
        const int n_in = (n0 & 1023) + wn + j * 16 + fr;
#pragma unroll
        for (int r = 0; r < 4; ++r) {
          const int m = m0 + wm + i * 16 + (fg << 2) + r;
          Vb[(size_t)m * E_ + n_in] = f2bf(acc[i][j][r] + br[j]);
        }
      }
  }
}

// ---------------------------------------------------------------------------
// In-LDS Stockham radix-4 FFT, N=4096 (6 stages), 256 thr. Result in A.
// ---------------------------------------------------------------------------
__device__ __forceinline__ float2 cmulf(float2 a, float2 b) {
  return make_float2(a.x * b.x - a.y * b.y, a.x * b.y + a.y * b.x);
}

__device__ void fft4096_r4(float2* __restrict__ A, float2* __restrict__ Bb,
                           int tid, float sign) {
  float2* cur = A;
  float2* nxt = Bb;
  const float TWO_PI = 6.28318530717958647692f;
  for (int Ns = 1; Ns < 4096; Ns *= 4) {
    __syncthreads();
    for (int j = tid; j < 1024; j += 256) {
      float2 v0 = cur[j];
      float2 v1 = cur[j + 1024];
      float2 v2 = cur[j + 2048];
      float2 v3 = cur[j + 3072];
      int r = j & (Ns - 1);
      float ang = sign * TWO_PI * (float)r / (float)(4 * Ns);
      float s1, c1;
      __sincosf(ang, &s1, &c1);
      float2 w1 = make_float2(c1, s1);
      float2 w2 = cmulf(w1, w1);
      float2 w3 = cmulf(w2, w1);
      v1 = cmulf(v1, w1);
      v2 = cmulf(v2, w2);
      v3 = cmulf(v3, w3);
      float2 t0 = make_float2(v0.x + v2.x, v0.y + v2.y);
      float2 t1 = make_float2(v0.x - v2.x, v0.y - v2.y);
      float2 t2 = make_float2(v1.x + v3.x, v1.y + v3.y);
      float2 t3 = make_float2(v1.x - v3.x, v1.y - v3.y);
      float2 t3i = make_float2(-sign * t3.y, sign * t3.x);
      int idxD = ((j - r) << 2) + r;
      nxt[idxD]          = make_float2(t0.x + t2.x, t0.y + t2.y);
      nxt[idxD + Ns]     = make_float2(t1.x + t3i.x, t1.y + t3i.y);
      nxt[idxD + 2 * Ns] = make_float2(t0.x - t2.x, t0.y - t2.y);
      nxt[idxD + 3 * Ns] = make_float2(t1.x - t3i.x, t1.y - t3i.y);
    }
    float2* tmp = cur; cur = nxt; nxt = tmp;
  }
  __syncthreads();
}

// ---------------------------------------------------------------------------
// Kernel 2: per-(b,h) correlation + softmax + attn@V.  One block per (b,h).
// ---------------------------------------------------------------------------
__global__ __launch_bounds__(256) void corr_attn(
    const float* __restrict__ QT, const float* __restrict__ KT,
    const unsigned short* __restrict__ Vb, float* __restrict__ out_flat) {
  __shared__ float2 bufA[L_];
  __shared__ float2 bufB[L_];
  __shared__ float2 S[L_ / 2 + 1];
  __shared__ float red[256];

  const int bh = blockIdx.x;
  const int b = bh >> 4, h = bh & (H_ - 1);
  const int tid = threadIdx.x;

  for (int f = tid; f <= L_ / 2; f += 256) S[f] = make_float2(0.f, 0.f);

  const size_t baseQK = (size_t)(b * E_ + h * D_) * L_;

  for (int d = 0; d < D_; ++d) {
    __syncthreads();
    const float* q = QT + baseQK + (size_t)d * L_;
    const float* k = KT + baseQK + (size_t)d * L_;
    for (int l = tid; l < L_; l += 256) bufA[l] = make_float2(q[l], k[l]);
    fft4096_r4(bufA, bufB, tid, -1.0f);
    for (int f = tid; f <= L_ / 2; f += 256) {
      float2 Zf = bufA[f];
      float2 Zc = bufA[(L_ - f) & (L_ - 1)];
      float ax = Zc.x, ay = -Zc.y;
      float qx = 0.5f * (Zf.x + ax), qy = 0.5f * (Zf.y + ay);
      float ux = Zf.x - ax, uy = Zf.y - ay;
      float kx = 0.5f * uy, ky = -0.5f * ux;
      S[f].x += qx * kx + qy * ky;
      S[f].y += qy * kx - qx * ky;
    }
  }
  __syncthreads();
  for (int f = tid; f < L_; f += 256) {
    float2 v;
    if (f <= L_ / 2) v = S[f];
    else { float2 s2 = S[L_ - f]; v = make_float2(s2.x, -s2.y); }
    bufA[f] = v;
  }
  fft4096_r4(bufA, bufB, tid, 1.0f);

  const float cscale = 1.0f / ((float)L_ * (float)D_);
  float lmax = -3.0e38f;
  for (int l = tid; l < L_; l += 256) lmax = fmaxf(lmax, bufA[l].x);
  red[tid] = lmax;
  __syncthreads();
  for (int s = 128; s > 0; s >>= 1) {
    if (tid < s) red[tid] = fmaxf(red[tid], red[tid + s]);
    __syncthreads();
  }
  const float gmax = red[0] * cscale;
  __syncthreads();
  float lsum = 0.f;
  for (int l = tid; l < L_; l += 256) {
    float w = __expf(bufA[l].x * cscale - gmax);
    bufA[l].x = w;
    lsum += w;
  }
  red[tid] = lsum;
  __syncthreads();
  for (int s = 128; s > 0; s >>= 1) {
    if (tid < s) red[tid] += red[tid + s];
    __syncthreads();
  }
  const float inv = 1.0f / red[0];
  __syncthreads();

  const int d = tid & 63, g = tid >> 6;
  const unsigned short* vb = Vb + (size_t)b * L_ * E_ + h * D_ + d;
  float acc = 0.f;
  for (int l = g; l < L_; l += 4)
    acc = fmaf(bufA[l].x, bf2f(vb[(size_t)l * E_]), acc);
  red[tid] = acc;
  __syncthreads();
  if (g == 0) {
    float t = red[d] + red[64 + d] + red[128 + d] + red[192 + d];
    out_flat[b * E_ + d * H_ + h] = t * inv;
  }
}

// ---------------------------------------------------------------------------
// Kernel 3: y[b,o] = bo[o] + sum_j flat[b,j] * Wo[o,j]
// ---------------------------------------------------------------------------
__global__ __launch_bounds__(256) void final_proj(
    const float* __restrict__ flat, const float* __restrict__ Wo,
    const float* __restrict__ bo, float* __restrict__ y) {
  __shared__ float sf[E_];
  const int b = blockIdx.x;
  for (int j = threadIdx.x; j < E_; j += 256) sf[j] = flat[b * E_ + j];
  __syncthreads();
  for (int o = threadIdx.x; o < E_; o += 256) {
    const float4* wr = (const float4*)(Wo + (size_t)o * E_);
    float s = 0.f;
#pragma unroll 4
    for (int j4 = 0; j4 < E_ / 4; ++j4) {
      float4 w = wr[j4];
      float4 f = *(const float4*)&sf[j4 * 4];
      s += w.x * f.x + w.y * f.y + w.z * f.z + w.w * f.w;
    }
    y[b * E_ + o] = s + bo[o];
  }
}

// ---------------------------------------------------------------------------
// Kernel 4: broadcast y (B,E) to out (B,L,E).
// ---------------------------------------------------------------------------
__global__ void broadcast_out(const float* __restrict__ y,
                              float4* __restrict__ out4) {
  const size_t total = (size_t)B_ * L_ * (E_ / 4);
  const float4* y4 = (const float4*)y;
  for (size_t i = (size_t)blockIdx.x * blockDim.x + threadIdx.x; i < total;
       i += (size_t)gridDim.x * blockDim.x) {
    size_t e4 = i & (E_ / 4 - 1);
    size_t b = i >> 20;
    out4[i] = y4[b * (E_ / 4) + e4];
  }
}

// ---------------------------------------------------------------------------
extern "C" void kernel_launch(void* const* d_in, const int* in_sizes, int n_in,
                              void* d_out, int out_size, void* d_ws,
                              size_t ws_size, hipStream_t stream) {
  const float* x  = (const float*)d_in[0];
  const float* Wq = (const float*)d_in[1];
  const float* bq = (const float*)d_in[2];
  const float* Wk = (const float*)d_in[3];
  const float* bk = (const float*)d_in[4];
  const float* Wv = (const float*)d_in[5];
  const float* bv = (const float*)d_in[6];
  const float* Wo = (const float*)d_in[7];
  const float* bo = (const float*)d_in[8];

  // ws layout (bytes): KT fp32 134217728 | Vb bf16 67108864 | Whi 6291456 |
  //                    Wlo 6291456 | flat 32768 | y 32768   => ~214 MB
  char* w = (char*)d_ws;
  float* KT            = (float*)w;
  unsigned short* Vb   = (unsigned short*)(w + 134217728);
  unsigned short* Whi  = (unsigned short*)(w + 201326592);
  unsigned short* Wlo  = (unsigned short*)(w + 207618048);
  float* flat          = (float*)(w + 213909504);
  float* y             = (float*)(w + 213942272);
  float* QT            = (float*)d_out;  // scratch; overwritten by broadcast

  conv_w<<<dim3(1024, 3), 256, 0, stream>>>(Wq, Wk, Wv, Whi, Wlo);
  qkv_gemm<<<dim3(24, 256), 256, 0, stream>>>(x, Whi, Wlo, bq, bk, bv, QT, KT, Vb);
  corr_attn<<<dim3(B_ * H_), 256, 0, stream>>>(QT, KT, Vb, flat);
  final_proj<<<dim3(B_), 256, 0, stream>>>(flat, Wo, bo, y);
  broadcast_out<<<dim3(2048), 256, 0, stream>>>(y, (float4*)d_out);
}

// Round 3
// 944.246 us; speedup vs baseline: 4.5555x; 1.9041x over previous
//
#include <hip/hip_runtime.h>
#include <hip/hip_bf16.h>
#include <math.h>

// Problem constants (AutoCorrelationAttention): B=8, L=4096, E=1024, H=16, D=64
#define B_ 8
#define L_ 4096
#define E_ 1024
#define H_ 16
#define D_ 64

typedef short short8 __attribute__((ext_vector_type(8)));
typedef float f32x4 __attribute__((ext_vector_type(4)));

__device__ __forceinline__ unsigned short f2bf(float f) {
  unsigned int u = __float_as_uint(f);
  unsigned int r = u + 0x7FFFu + ((u >> 16) & 1u);
  return (unsigned short)(r >> 16);
}
__device__ __forceinline__ float bf2f(unsigned short h) {
  return __uint_as_float(((unsigned int)h) << 16);
}

#define GLDS16(g, l)                                                     \
  __builtin_amdgcn_global_load_lds(                                      \
      (const __attribute__((address_space(1))) void*)(g),                \
      (__attribute__((address_space(3))) void*)(l), 16, 0, 0)

// ---------------------------------------------------------------------------
// Kernel 0: split Wq/Wk/Wv into bf16 hi/lo, fused [3072][1024] layout.
// ---------------------------------------------------------------------------
__global__ __launch_bounds__(256) void conv_w(
    const float* __restrict__ Wq, const float* __restrict__ Wk,
    const float* __restrict__ Wv, unsigned short* __restrict__ Whi,
    unsigned short* __restrict__ Wlo) {
  const int wsel = blockIdx.y;
  const float* W = (wsel == 0) ? Wq : (wsel == 1) ? Wk : Wv;
  size_t i = ((size_t)blockIdx.x * 256 + threadIdx.x) * 4;
  float4 f = *(const float4*)(W + i);
  size_t o = (size_t)wsel * (1024 * 1024) + i;
  float ff[4] = {f.x, f.y, f.z, f.w};
  unsigned short hh[4], ll[4];
#pragma unroll
  for (int e = 0; e < 4; ++e) {
    hh[e] = f2bf(ff[e]);
    ll[e] = f2bf(ff[e] - bf2f(hh[e]));
  }
  *(ushort4*)(Whi + o) = make_ushort4(hh[0], hh[1], hh[2], hh[3]);
  *(ushort4*)(Wlo + o) = make_ushort4(ll[0], ll[1], ll[2], ll[3]);
}

// ---------------------------------------------------------------------------
// Kernel 1: fused QKV projection, split-bf16 MFMA GEMM (3-term, fp32-grade).
// (unchanged from R2 — passed at absmax 1.95e-3)
// ---------------------------------------------------------------------------
__global__ __launch_bounds__(256) void qkv_gemm(
    const float* __restrict__ x, const unsigned short* __restrict__ Whi,
    const unsigned short* __restrict__ Wlo, const float* __restrict__ bq,
    const float* __restrict__ bk, const float* __restrict__ bv,
    float* __restrict__ QT, float* __restrict__ KT,
    unsigned short* __restrict__ Vb) {
  __shared__ unsigned short sAhi[128 * 64];
  __shared__ unsigned short sAlo[128 * 64];
  __shared__ unsigned short sBhi[128 * 64];
  __shared__ unsigned short sBlo[128 * 64];

  const int tid = threadIdx.x;
  const int wid = tid >> 6, lane = tid & 63;
  const int n0 = blockIdx.x * 128;
  const int m0 = blockIdx.y * 128;

  f32x4 acc[4][4];
#pragma unroll
  for (int i = 0; i < 4; ++i)
#pragma unroll
    for (int j = 0; j < 4; ++j) acc[i][j] = (f32x4){0.f, 0.f, 0.f, 0.f};

  const int brow = lane >> 3;
  const int bcol = (lane & 7) * 8;
  const int arow = tid >> 3;
  const int acol = (tid & 7) * 8;
  const int wm = (wid >> 1) * 64, wn = (wid & 1) * 64;
  const int fr = lane & 15, fg = lane >> 4;

  for (int k0 = 0; k0 < E_; k0 += 64) {
    __syncthreads();
#pragma unroll
    for (int q = 0; q < 4; ++q) {
      const int rb = (wid * 4 + q) * 8;
      GLDS16(Whi + (size_t)(n0 + rb + brow) * E_ + k0 + bcol, &sBhi[rb * 64]);
      GLDS16(Wlo + (size_t)(n0 + rb + brow) * E_ + k0 + bcol, &sBlo[rb * 64]);
    }
#pragma unroll
    for (int q = 0; q < 4; ++q) {
      float af[8];
      const float* g = x + (size_t)(m0 + q * 32 + arow) * E_ + k0 + acol;
      *(float4*)&af[0] = *(const float4*)(g);
      *(float4*)&af[4] = *(const float4*)(g + 4);
      short8 vh, vl;
#pragma unroll
      for (int e = 0; e < 8; ++e) {
        unsigned short h = f2bf(af[e]);
        vh[e] = (short)h;
        vl[e] = (short)f2bf(af[e] - bf2f(h));
      }
      *(short8*)&sAhi[q * 2048 + tid * 8] = vh;
      *(short8*)&sAlo[q * 2048 + tid * 8] = vl;
    }
    __syncthreads();
#pragma unroll
    for (int p = 0; p < 3; ++p) {
      const unsigned short* ab = (p == 1) ? sAlo : sAhi;
      const unsigned short* bb = (p == 2) ? sBlo : sBhi;
      short8 afr[4][2], bfr[4][2];
#pragma unroll
      for (int i = 0; i < 4; ++i)
#pragma unroll
        for (int kk = 0; kk < 2; ++kk) {
          afr[i][kk] = *(const short8*)&ab[(wm + i * 16 + fr) * 64 + kk * 32 + fg * 8];
          bfr[i][kk] = *(const short8*)&bb[(wn + i * 16 + fr) * 64 + kk * 32 + fg * 8];
        }
#pragma unroll
      for (int i = 0; i < 4; ++i)
#pragma unroll
        for (int j = 0; j < 4; ++j)
#pragma unroll
          for (int kk = 0; kk < 2; ++kk)
            acc[i][j] = __builtin_amdgcn_mfma_f32_16x16x32_bf16(
                afr[i][kk], bfr[j][kk], acc[i][j], 0, 0, 0);
    }
  }

  const int wsel = n0 >> 10;
  const float* bias = (wsel == 0) ? bq : (wsel == 1) ? bk : bv;
  float br[4];
#pragma unroll
  for (int j = 0; j < 4; ++j)
    br[j] = bias[(n0 & 1023) + wn + j * 16 + fr];

  if (wsel < 2) {
    float* T = (wsel == 0) ? QT : KT;
    const int b = m0 >> 12;
    const int lbase = (m0 & 4095) + wm + (fg << 2);
#pragma unroll
    for (int i = 0; i < 4; ++i)
#pragma unroll
      for (int j = 0; j < 4; ++j) {
        const int n_in = (n0 & 1023) + wn + j * 16 + fr;
        float4 v = make_float4(acc[i][j][0] + br[j], acc[i][j][1] + br[j],
                               acc[i][j][2] + br[j], acc[i][j][3] + br[j]);
        *(float4*)&T[((size_t)(b << 10) + n_in) * L_ + lbase + i * 16] = v;
      }
  } else {
#pragma unroll
    for (int i = 0; i < 4; ++i)
#pragma unroll
      for (int j = 0; j < 4; ++j) {
        const int n_in = (n0 & 1023) + wn + j * 16 + fr;
#pragma unroll
        for (int r = 0; r < 4; ++r) {
          const int m = m0 + wm + i * 16 + (fg << 2) + r;
          Vb[(size_t)m * E_ + n_in] = f2bf(acc[i][j][r] + br[j]);
        }
      }
  }
}

// ---------------------------------------------------------------------------
// In-LDS Stockham radix-4 FFT, N=4096, 1024 threads: one butterfly per
// thread per stage, 6 stages, result in A.
// ---------------------------------------------------------------------------
__device__ __forceinline__ float2 cmulf(float2 a, float2 b) {
  return make_float2(a.x * b.x - a.y * b.y, a.x * b.y + a.y * b.x);
}

__device__ __forceinline__ void fft4096_1024(float2* __restrict__ A,
                                             float2* __restrict__ Bb,
                                             int tid, float sign) {
  float2* cur = A;
  float2* nxt = Bb;
  const float TWO_PI = 6.28318530717958647692f;
#pragma unroll
  for (int st = 0; st < 6; ++st) {
    const int Ns = 1 << (2 * st);
    __syncthreads();
    const int j = tid;
    float2 v0 = cur[j];
    float2 v1 = cur[j + 1024];
    float2 v2 = cur[j + 2048];
    float2 v3 = cur[j + 3072];
    const int r = j & (Ns - 1);
    float ang = sign * TWO_PI * (float)r / (float)(4 * Ns);
    float s1, c1;
    __sincosf(ang, &s1, &c1);
    float2 w1 = make_float2(c1, s1);
    float2 w2 = cmulf(w1, w1);
    float2 w3 = cmulf(w2, w1);
    v1 = cmulf(v1, w1);
    v2 = cmulf(v2, w2);
    v3 = cmulf(v3, w3);
    float2 t0 = make_float2(v0.x + v2.x, v0.y + v2.y);
    float2 t1 = make_float2(v0.x - v2.x, v0.y - v2.y);
    float2 t2 = make_float2(v1.x + v3.x, v1.y + v3.y);
    float2 t3 = make_float2(v1.x - v3.x, v1.y - v3.y);
    float2 t3i = make_float2(-sign * t3.y, sign * t3.x);
    const int idxD = ((j - r) << 2) + r;
    nxt[idxD]          = make_float2(t0.x + t2.x, t0.y + t2.y);
    nxt[idxD + Ns]     = make_float2(t1.x + t3i.x, t1.y + t3i.y);
    nxt[idxD + 2 * Ns] = make_float2(t0.x - t2.x, t0.y - t2.y);
    nxt[idxD + 3 * Ns] = make_float2(t1.x - t3i.x, t1.y - t3i.y);
    float2* tmp = cur; cur = nxt; nxt = tmp;
  }
  __syncthreads();
}

// ---------------------------------------------------------------------------
// Kernel 2a: per-(b,h,ds) partial cross-spectrum. 8 packed FFTs per block.
// S packed: S[0].y holds the (real) Nyquist bin -> LDS exactly 80 KiB,
// 2 blocks/CU.
// ---------------------------------------------------------------------------
__global__ __launch_bounds__(1024) void corr_fft(
    const float* __restrict__ QT, const float* __restrict__ KT,
    float2* __restrict__ Spart) {
  __shared__ float2 bufA[L_];      // 32 KB
  __shared__ float2 bufB[L_];      // 32 KB
  __shared__ float2 S[L_ / 2];     // 16 KB (Nyquist packed into S[0].y)

  const int bh = blockIdx.x, ds = blockIdx.y;
  const int b = bh >> 4, h = bh & (H_ - 1);
  const int tid = threadIdx.x;

  for (int f = tid; f < L_ / 2; f += 1024) S[f] = make_float2(0.f, 0.f);

  const size_t baseQK = (size_t)(b * E_ + h * D_) * L_;

  for (int dd = 0; dd < 8; ++dd) {
    const int d = ds * 8 + dd;
    __syncthreads();  // prior-iteration bufA readers done / S init visible
    const float* q = QT + baseQK + (size_t)d * L_;
    const float* k = KT + baseQK + (size_t)d * L_;
    float4 q4 = *(const float4*)(q + tid * 4);
    float4 k4 = *(const float4*)(k + tid * 4);
    *(float4*)&bufA[tid * 4]     = make_float4(q4.x, k4.x, q4.y, k4.y);
    *(float4*)&bufA[tid * 4 + 2] = make_float4(q4.z, k4.z, q4.w, k4.w);
    fft4096_1024(bufA, bufB, tid, -1.0f);
    // Hermitian split: Qf = (Z + conj(Z[-f]))/2 ; Kf = (Z - conj(Z[-f]))/(2i)
    for (int f = tid; f <= L_ / 2; f += 1024) {
      float2 Zf = bufA[f];
      float2 Zc = bufA[(L_ - f) & (L_ - 1)];
      float ax = Zc.x, ay = -Zc.y;
      float qx = 0.5f * (Zf.x + ax), qy = 0.5f * (Zf.y + ay);
      float ux = Zf.x - ax, uy = Zf.y - ay;
      float kx = 0.5f * uy, ky = -0.5f * ux;
      float re = qx * kx + qy * ky;
      float im = qy * kx - qx * ky;
      if (f == 0) S[0].x += re;             // DC (real)
      else if (f == L_ / 2) S[0].y += re;   // Nyquist (real), packed
      else { S[f].x += re; S[f].y += im; }
    }
  }
  __syncthreads();
  float2* out = Spart + (size_t)(bh * 8 + ds) * (L_ / 2);
  for (int f = tid; f < L_ / 2; f += 1024) out[f] = S[f];
}

// ---------------------------------------------------------------------------
// Kernel 2b: per-(b,h) reduce partials -> inverse FFT -> softmax -> attn@V.
// ---------------------------------------------------------------------------
__global__ __launch_bounds__(1024) void corr_post(
    const float2* __restrict__ Spart, const unsigned short* __restrict__ Vb,
    float* __restrict__ out_flat) {
  __shared__ float2 bufA[L_];   // 32 KB
  __shared__ float2 bufB[L_];   // 32 KB
  __shared__ float red[1024];   // 4 KB

  const int bh = blockIdx.x;
  const int b = bh >> 4, h = bh & (H_ - 1);
  const int tid = threadIdx.x;

  const float2* sp = Spart + (size_t)(bh * 8) * (L_ / 2);
  for (int f = tid; f < L_ / 2; f += 1024) {
    float2 s = make_float2(0.f, 0.f);
#pragma unroll
    for (int ds = 0; ds < 8; ++ds) {
      float2 p = sp[(size_t)ds * (L_ / 2) + f];
      s.x += p.x;
      s.y += p.y;
    }
    if (f == 0) {
      bufA[0] = make_float2(s.x, 0.f);
      bufA[L_ / 2] = make_float2(s.y, 0.f);  // unpacked Nyquist
    } else {
      bufA[f] = s;
      bufA[L_ - f] = make_float2(s.x, -s.y);
    }
  }
  fft4096_1024(bufA, bufB, tid, 1.0f);  // leading __syncthreads covers writes

  const float cscale = 1.0f / ((float)L_ * (float)D_);
  float lmax = -3.0e38f;
#pragma unroll
  for (int q = 0; q < 4; ++q) lmax = fmaxf(lmax, bufA[tid + q * 1024].x);
  red[tid] = lmax;
  __syncthreads();
  for (int s = 512; s > 0; s >>= 1) {
    if (tid < s) red[tid] = fmaxf(red[tid], red[tid + s]);
    __syncthreads();
  }
  const float gmax = red[0] * cscale;
  __syncthreads();
  float lsum = 0.f;
#pragma unroll
  for (int q = 0; q < 4; ++q) {
    float w = __expf(bufA[tid + q * 1024].x * cscale - gmax);
    bufA[tid + q * 1024].x = w;
    lsum += w;
  }
  red[tid] = lsum;
  __syncthreads();
  for (int s = 512; s > 0; s >>= 1) {
    if (tid < s) red[tid] += red[tid + s];
    __syncthreads();
  }
  const float inv = 1.0f / red[0];
  __syncthreads();

  // attn@V: 16 l-groups x 64 d lanes
  const int d = tid & 63, g = tid >> 6;
  const unsigned short* vb = Vb + (size_t)b * L_ * E_ + h * D_ + d;
  float acc = 0.f;
  for (int l = g; l < L_; l += 16)
    acc = fmaf(bufA[l].x, bf2f(vb[(size_t)l * E_]), acc);
  red[tid] = acc;
  __syncthreads();
  if (tid < 64) {
    float t = 0.f;
#pragma unroll
    for (int g2 = 0; g2 < 16; ++g2) t += red[g2 * 64 + tid];
    out_flat[b * E_ + tid * H_ + h] = t * inv;  // j = d*H + h
  }
}

// ---------------------------------------------------------------------------
// Kernel 3: y[b,o] = bo[o] + sum_j flat[b,j] * Wo[o,j]  (128 blocks)
// ---------------------------------------------------------------------------
__global__ __launch_bounds__(256) void final_proj(
    const float* __restrict__ flat, const float* __restrict__ Wo,
    const float* __restrict__ bo, float* __restrict__ y) {
  __shared__ float sf[E_];
  const int b = blockIdx.y;
  const int o0 = blockIdx.x * 64;
  for (int j = threadIdx.x; j < E_; j += 256) sf[j] = flat[b * E_ + j];
  __syncthreads();
  const int oo = threadIdx.x >> 2, part = threadIdx.x & 3;
  const int o = o0 + oo;
  const float4* wr = (const float4*)(Wo + (size_t)o * E_) + part * 64;
  const float4* fr = (const float4*)sf + part * 64;
  float s = 0.f;
#pragma unroll 8
  for (int i = 0; i < 64; ++i) {
    float4 w = wr[i];
    float4 f = fr[i];
    s += w.x * f.x + w.y * f.y + w.z * f.z + w.w * f.w;
  }
  s += __shfl_xor(s, 1);
  s += __shfl_xor(s, 2);
  if (part == 0) y[b * E_ + o] = s + bo[o];
}

// ---------------------------------------------------------------------------
// Kernel 4: broadcast y (B,E) to out (B,L,E).
// ---------------------------------------------------------------------------
__global__ void broadcast_out(const float* __restrict__ y,
                              float4* __restrict__ out4) {
  const size_t total = (size_t)B_ * L_ * (E_ / 4);
  const float4* y4 = (const float4*)y;
  for (size_t i = (size_t)blockIdx.x * blockDim.x + threadIdx.x; i < total;
       i += (size_t)gridDim.x * blockDim.x) {
    size_t e4 = i & (E_ / 4 - 1);
    size_t b = i >> 20;
    out4[i] = y4[b * (E_ / 4) + e4];
  }
}

// ---------------------------------------------------------------------------
extern "C" void kernel_launch(void* const* d_in, const int* in_sizes, int n_in,
                              void* d_out, int out_size, void* d_ws,
                              size_t ws_size, hipStream_t stream) {
  const float* x  = (const float*)d_in[0];
  const float* Wq = (const float*)d_in[1];
  const float* bq = (const float*)d_in[2];
  const float* Wk = (const float*)d_in[3];
  const float* bk = (const float*)d_in[4];
  const float* Wv = (const float*)d_in[5];
  const float* bv = (const float*)d_in[6];
  const float* Wo = (const float*)d_in[7];
  const float* bo = (const float*)d_in[8];

  // ws layout (bytes):
  //   KT fp32      @ 0          (134217728)
  //   Vb bf16      @ 134217728  (67108864)
  //   Whi bf16     @ 201326592  (6291456)
  //   Wlo bf16     @ 207618048  (6291456)
  //   Spart f32x2  @ 213909504  (16777216)   128*8 partial spectra of 2048
  //   flat f32     @ 230686720  (32768)
  //   y f32        @ 230719488  (32768)      => ~230.8 MB
  char* w = (char*)d_ws;
  float* KT            = (float*)w;
  unsigned short* Vb   = (unsigned short*)(w + 134217728);
  unsigned short* Whi  = (unsigned short*)(w + 201326592);
  unsigned short* Wlo  = (unsigned short*)(w + 207618048);
  float2* Spart        = (float2*)(w + 213909504);
  float* flat          = (float*)(w + 230686720);
  float* y             = (float*)(w + 230719488);
  float* QT            = (float*)d_out;  // scratch; overwritten by broadcast

  conv_w<<<dim3(1024, 3), 256, 0, stream>>>(Wq, Wk, Wv, Whi, Wlo);
  qkv_gemm<<<dim3(24, 256), 256, 0, stream>>>(x, Whi, Wlo, bq, bk, bv, QT, KT, Vb);
  corr_fft<<<dim3(B_ * H_, 8), 1024, 0, stream>>>(QT, KT, Spart);
  corr_post<<<dim3(B_ * H_), 1024, 0, stream>>>(Spart, Vb, flat);
  final_proj<<<dim3(16, B_), 256, 0, stream>>>(flat, Wo, bo, y);
  broadcast_out<<<dim3(2048), 256, 0, stream>>>(y, (float4*)d_out);
}

// Round 4
// 900.493 us; speedup vs baseline: 4.7769x; 1.0486x over previous
//
#include <hip/hip_runtime.h>
#include <hip/hip_bf16.h>
#include <math.h>

// Problem constants (AutoCorrelationAttention): B=8, L=4096, E=1024, H=16, D=64
#define B_ 8
#define L_ 4096
#define E_ 1024
#define H_ 16
#define D_ 64

typedef short short8 __attribute__((ext_vector_type(8)));
typedef float f32x4 __attribute__((ext_vector_type(4)));

__device__ __forceinline__ unsigned short f2bf(float f) {
  unsigned int u = __float_as_uint(f);
  unsigned int r = u + 0x7FFFu + ((u >> 16) & 1u);
  return (unsigned short)(r >> 16);
}
__device__ __forceinline__ float bf2f(unsigned short h) {
  return __uint_as_float(((unsigned int)h) << 16);
}

#define GLDS16(g, l)                                                     \
  __builtin_amdgcn_global_load_lds(                                      \
      (const __attribute__((address_space(1))) void*)(g),                \
      (__attribute__((address_space(3))) void*)(l), 16, 0, 0)

// ---------------------------------------------------------------------------
// Kernel 0: split Wq/Wk/Wv into bf16 hi/lo, fused [3072][1024] layout.
// ---------------------------------------------------------------------------
__global__ __launch_bounds__(256) void conv_w(
    const float* __restrict__ Wq, const float* __restrict__ Wk,
    const float* __restrict__ Wv, unsigned short* __restrict__ Whi,
    unsigned short* __restrict__ Wlo) {
  const int wsel = blockIdx.y;
  const float* W = (wsel == 0) ? Wq : (wsel == 1) ? Wk : Wv;
  size_t i = ((size_t)blockIdx.x * 256 + threadIdx.x) * 4;
  float4 f = *(const float4*)(W + i);
  size_t o = (size_t)wsel * (1024 * 1024) + i;
  float ff[4] = {f.x, f.y, f.z, f.w};
  unsigned short hh[4], ll[4];
#pragma unroll
  for (int e = 0; e < 4; ++e) {
    hh[e] = f2bf(ff[e]);
    ll[e] = f2bf(ff[e] - bf2f(hh[e]));
  }
  *(ushort4*)(Whi + o) = make_ushort4(hh[0], hh[1], hh[2], hh[3]);
  *(ushort4*)(Wlo + o) = make_ushort4(ll[0], ll[1], ll[2], ll[3]);
}

// ---------------------------------------------------------------------------
// Kernel 1: fused QKV projection, split-bf16 MFMA GEMM (3-term, fp32-grade).
// T2 XOR-swizzled LDS tiles (16B block p = c ^ (row&7) within 128B rows):
//   - B: linear global_load_lds dest + inverse-swizzled GLOBAL source col
//   - A: reg-staged, ds_write to swizzled block
//   - fragment ds_read_b128 at swizzled block  (row&7 == fr&7 for all frags)
// ---------------------------------------------------------------------------
__global__ __launch_bounds__(256) void qkv_gemm(
    const float* __restrict__ x, const unsigned short* __restrict__ Whi,
    const unsigned short* __restrict__ Wlo, const float* __restrict__ bq,
    const float* __restrict__ bk, const float* __restrict__ bv,
    float* __restrict__ QT, float* __restrict__ KT,
    unsigned short* __restrict__ Vb) {
  __shared__ unsigned short sAhi[128 * 64];
  __shared__ unsigned short sAlo[128 * 64];
  __shared__ unsigned short sBhi[128 * 64];
  __shared__ unsigned short sBlo[128 * 64];

  const int tid = threadIdx.x;
  const int wid = tid >> 6, lane = tid & 63;
  const int n0 = blockIdx.x * 128;
  const int m0 = blockIdx.y * 128;

  f32x4 acc[4][4];
#pragma unroll
  for (int i = 0; i < 4; ++i)
#pragma unroll
    for (int j = 0; j < 4; ++j) acc[i][j] = (f32x4){0.f, 0.f, 0.f, 0.f};

  const int brow = lane >> 3;                              // row within 8-row block
  const int bcol = (((lane & 7) ^ (brow & 7)) & 7) * 8;    // swizzled source col
  const int arow = tid >> 3;                               // row within 32-row quarter
  const int acol = (tid & 7) * 8;                          // natural source col
  const int awz  = ((tid & 7) ^ (arow & 7)) * 8;           // swizzled LDS block
  const int wm = (wid >> 1) * 64, wn = (wid & 1) * 64;
  const int fr = lane & 15, fg = lane >> 4;
  const int fr7 = fr & 7;

  for (int k0 = 0; k0 < E_; k0 += 64) {
    __syncthreads();
    // ---- stage B hi/lo direct to LDS (linear dest, pre-swizzled source)
#pragma unroll
    for (int q = 0; q < 4; ++q) {
      const int rb = (wid * 4 + q) * 8;
      GLDS16(Whi + (size_t)(n0 + rb + brow) * E_ + k0 + bcol, &sBhi[rb * 64]);
      GLDS16(Wlo + (size_t)(n0 + rb + brow) * E_ + k0 + bcol, &sBlo[rb * 64]);
    }
    // ---- stage A: fp32 -> hi/lo bf16, ds_write to swizzled block
#pragma unroll
    for (int q = 0; q < 4; ++q) {
      float af[8];
      const float* g = x + (size_t)(m0 + q * 32 + arow) * E_ + k0 + acol;
      *(float4*)&af[0] = *(const float4*)(g);
      *(float4*)&af[4] = *(const float4*)(g + 4);
      short8 vh, vl;
#pragma unroll
      for (int e = 0; e < 8; ++e) {
        unsigned short h = f2bf(af[e]);
        vh[e] = (short)h;
        vl[e] = (short)f2bf(af[e] - bf2f(h));
      }
      *(short8*)&sAhi[q * 2048 + arow * 64 + awz] = vh;
      *(short8*)&sAlo[q * 2048 + arow * 64 + awz] = vl;
    }
    __syncthreads();
    // ---- compute: 3 passes x 32 MFMA, swizzled fragment reads
#pragma unroll
    for (int p = 0; p < 3; ++p) {
      const unsigned short* ab = (p == 1) ? sAlo : sAhi;
      const unsigned short* bb = (p == 2) ? sBlo : sBhi;
      short8 afr[4][2], bfr[4][2];
#pragma unroll
      for (int i = 0; i < 4; ++i)
#pragma unroll
        for (int kk = 0; kk < 2; ++kk) {
          const int blk = (((kk * 4 + fg) ^ fr7) << 3);
          afr[i][kk] = *(const short8*)&ab[(wm + i * 16 + fr) * 64 + blk];
          bfr[i][kk] = *(const short8*)&bb[(wn + i * 16 + fr) * 64 + blk];
        }
#pragma unroll
      for (int i = 0; i < 4; ++i)
#pragma unroll
        for (int j = 0; j < 4; ++j)
#pragma unroll
          for (int kk = 0; kk < 2; ++kk)
            acc[i][j] = __builtin_amdgcn_mfma_f32_16x16x32_bf16(
                afr[i][kk], bfr[j][kk], acc[i][j], 0, 0, 0);
    }
  }

  const int wsel = n0 >> 10;
  const float* bias = (wsel == 0) ? bq : (wsel == 1) ? bk : bv;
  float br[4];
#pragma unroll
  for (int j = 0; j < 4; ++j)
    br[j] = bias[(n0 & 1023) + wn + j * 16 + fr];

  if (wsel < 2) {
    float* T = (wsel == 0) ? QT : KT;
    const int b = m0 >> 12;
    const int lbase = (m0 & 4095) + wm + (fg << 2);
#pragma unroll
    for (int i = 0; i < 4; ++i)
#pragma unroll
      for (int j = 0; j < 4; ++j) {
        const int n_in = (n0 & 1023) + wn + j * 16 + fr;
        float4 v = make_float4(acc[i][j][0] + br[j], acc[i][j][1] + br[j],
                               acc[i][j][2] + br[j], acc[i][j][3] + br[j]);
        *(float4*)&T[((size_t)(b << 10) + n_in) * L_ + lbase + i * 16] = v;
      }
  } else {
#pragma unroll
    for (int i = 0; i < 4; ++i)
#pragma unroll
      for (int j = 0; j < 4; ++j) {
        const int n_in = (n0 & 1023) + wn + j * 16 + fr;
#pragma unroll
        for (int r = 0; r < 4; ++r) {
          const int m = m0 + wm + i * 16 + (fg << 2) + r;
          Vb[(size_t)m * E_ + n_in] = f2bf(acc[i][j][r] + br[j]);
        }
      }
  }
}

// ---------------------------------------------------------------------------
// In-LDS Stockham radix-4 FFT, N=4096, 1024 threads: one butterfly per
// thread per stage, 6 stages, result in A.
// ---------------------------------------------------------------------------
__device__ __forceinline__ float2 cmulf(float2 a, float2 b) {
  return make_float2(a.x * b.x - a.y * b.y, a.x * b.y + a.y * b.x);
}

__device__ __forceinline__ void fft4096_1024(float2* __restrict__ A,
                                             float2* __restrict__ Bb,
                                             int tid, float sign) {
  float2* cur = A;
  float2* nxt = Bb;
  const float TWO_PI = 6.28318530717958647692f;
#pragma unroll
  for (int st = 0; st < 6; ++st) {
    const int Ns = 1 << (2 * st);
    __syncthreads();
    const int j = tid;
    float2 v0 = cur[j];
    float2 v1 = cur[j + 1024];
    float2 v2 = cur[j + 2048];
    float2 v3 = cur[j + 3072];
    const int r = j & (Ns - 1);
    float ang = sign * TWO_PI * (float)r / (float)(4 * Ns);
    float s1, c1;
    __sincosf(ang, &s1, &c1);
    float2 w1 = make_float2(c1, s1);
    float2 w2 = cmulf(w1, w1);
    float2 w3 = cmulf(w2, w1);
    v1 = cmulf(v1, w1);
    v2 = cmulf(v2, w2);
    v3 = cmulf(v3, w3);
    float2 t0 = make_float2(v0.x + v2.x, v0.y + v2.y);
    float2 t1 = make_float2(v0.x - v2.x, v0.y - v2.y);
    float2 t2 = make_float2(v1.x + v3.x, v1.y + v3.y);
    float2 t3 = make_float2(v1.x - v3.x, v1.y - v3.y);
    float2 t3i = make_float2(-sign * t3.y, sign * t3.x);
    const int idxD = ((j - r) << 2) + r;
    nxt[idxD]          = make_float2(t0.x + t2.x, t0.y + t2.y);
    nxt[idxD + Ns]     = make_float2(t1.x + t3i.x, t1.y + t3i.y);
    nxt[idxD + 2 * Ns] = make_float2(t0.x - t2.x, t0.y - t2.y);
    nxt[idxD + 3 * Ns] = make_float2(t1.x - t3i.x, t1.y - t3i.y);
    float2* tmp = cur; cur = nxt; nxt = tmp;
  }
  __syncthreads();
}

// ---------------------------------------------------------------------------
// Kernel 2a: per-(b,h,ds) partial cross-spectrum. 8 packed FFTs per block.
// ---------------------------------------------------------------------------
__global__ __launch_bounds__(1024) void corr_fft(
    const float* __restrict__ QT, const float* __restrict__ KT,
    float2* __restrict__ Spart) {
  __shared__ float2 bufA[L_];      // 32 KB
  __shared__ float2 bufB[L_];      // 32 KB
  __shared__ float2 S[L_ / 2];     // 16 KB (Nyquist packed into S[0].y)

  const int bh = blockIdx.x, ds = blockIdx.y;
  const int b = bh >> 4, h = bh & (H_ - 1);
  const int tid = threadIdx.x;

  for (int f = tid; f < L_ / 2; f += 1024) S[f] = make_float2(0.f, 0.f);

  const size_t baseQK = (size_t)(b * E_ + h * D_) * L_;

  for (int dd = 0; dd < 8; ++dd) {
    const int d = ds * 8 + dd;
    __syncthreads();
    const float* q = QT + baseQK + (size_t)d * L_;
    const float* k = KT + baseQK + (size_t)d * L_;
    float4 q4 = *(const float4*)(q + tid * 4);
    float4 k4 = *(const float4*)(k + tid * 4);
    *(float4*)&bufA[tid * 4]     = make_float4(q4.x, k4.x, q4.y, k4.y);
    *(float4*)&bufA[tid * 4 + 2] = make_float4(q4.z, k4.z, q4.w, k4.w);
    fft4096_1024(bufA, bufB, tid, -1.0f);
    for (int f = tid; f <= L_ / 2; f += 1024) {
      float2 Zf = bufA[f];
      float2 Zc = bufA[(L_ - f) & (L_ - 1)];
      float ax = Zc.x, ay = -Zc.y;
      float qx = 0.5f * (Zf.x + ax), qy = 0.5f * (Zf.y + ay);
      float ux = Zf.x - ax, uy = Zf.y - ay;
      float kx = 0.5f * uy, ky = -0.5f * ux;
      float re = qx * kx + qy * ky;
      float im = qy * kx - qx * ky;
      if (f == 0) S[0].x += re;
      else if (f == L_ / 2) S[0].y += re;
      else { S[f].x += re; S[f].y += im; }
    }
  }
  __syncthreads();
  float2* out = Spart + (size_t)(bh * 8 + ds) * (L_ / 2);
  for (int f = tid; f < L_ / 2; f += 1024) out[f] = S[f];
}

// ---------------------------------------------------------------------------
// Kernel 2b: per-(b,h) reduce partials -> inverse FFT -> softmax -> attn@V.
// ---------------------------------------------------------------------------
__global__ __launch_bounds__(1024) void corr_post(
    const float2* __restrict__ Spart, const unsigned short* __restrict__ Vb,
    float* __restrict__ out_flat) {
  __shared__ float2 bufA[L_];
  __shared__ float2 bufB[L_];
  __shared__ float red[1024];

  const int bh = blockIdx.x;
  const int b = bh >> 4, h = bh & (H_ - 1);
  const int tid = threadIdx.x;

  const float2* sp = Spart + (size_t)(bh * 8) * (L_ / 2);
  for (int f = tid; f < L_ / 2; f += 1024) {
    float2 s = make_float2(0.f, 0.f);
#pragma unroll
    for (int ds = 0; ds < 8; ++ds) {
      float2 p = sp[(size_t)ds * (L_ / 2) + f];
      s.x += p.x;
      s.y += p.y;
    }
    if (f == 0) {
      bufA[0] = make_float2(s.x, 0.f);
      bufA[L_ / 2] = make_float2(s.y, 0.f);
    } else {
      bufA[f] = s;
      bufA[L_ - f] = make_float2(s.x, -s.y);
    }
  }
  fft4096_1024(bufA, bufB, tid, 1.0f);

  const float cscale = 1.0f / ((float)L_ * (float)D_);
  float lmax = -3.0e38f;
#pragma unroll
  for (int q = 0; q < 4; ++q) lmax = fmaxf(lmax, bufA[tid + q * 1024].x);
  red[tid] = lmax;
  __syncthreads();
  for (int s = 512; s > 0; s >>= 1) {
    if (tid < s) red[tid] = fmaxf(red[tid], red[tid + s]);
    __syncthreads();
  }
  const float gmax = red[0] * cscale;
  __syncthreads();
  float lsum = 0.f;
#pragma unroll
  for (int q = 0; q < 4; ++q) {
    float w = __expf(bufA[tid + q * 1024].x * cscale - gmax);
    bufA[tid + q * 1024].x = w;
    lsum += w;
  }
  red[tid] = lsum;
  __syncthreads();
  for (int s = 512; s > 0; s >>= 1) {
    if (tid < s) red[tid] += red[tid + s];
    __syncthreads();
  }
  const float inv = 1.0f / red[0];
  __syncthreads();

  const int d = tid & 63, g = tid >> 6;
  const unsigned short* vb = Vb + (size_t)b * L_ * E_ + h * D_ + d;
  float acc = 0.f;
  for (int l = g; l < L_; l += 16)
    acc = fmaf(bufA[l].x, bf2f(vb[(size_t)l * E_]), acc);
  red[tid] = acc;
  __syncthreads();
  if (tid < 64) {
    float t = 0.f;
#pragma unroll
    for (int g2 = 0; g2 < 16; ++g2) t += red[g2 * 64 + tid];
    out_flat[b * E_ + tid * H_ + h] = t * inv;
  }
}

// ---------------------------------------------------------------------------
// Kernel 3: y[b,o] = bo[o] + sum_j flat[b,j] * Wo[o,j]  (128 blocks)
// ---------------------------------------------------------------------------
__global__ __launch_bounds__(256) void final_proj(
    const float* __restrict__ flat, const float* __restrict__ Wo,
    const float* __restrict__ bo, float* __restrict__ y) {
  __shared__ float sf[E_];
  const int b = blockIdx.y;
  const int o0 = blockIdx.x * 64;
  for (int j = threadIdx.x; j < E_; j += 256) sf[j] = flat[b * E_ + j];
  __syncthreads();
  const int oo = threadIdx.x >> 2, part = threadIdx.x & 3;
  const int o = o0 + oo;
  const float4* wr = (const float4*)(Wo + (size_t)o * E_) + part * 64;
  const float4* fr = (const float4*)sf + part * 64;
  float s = 0.f;
#pragma unroll 8
  for (int i = 0; i < 64; ++i) {
    float4 w = wr[i];
    float4 f = fr[i];
    s += w.x * f.x + w.y * f.y + w.z * f.z + w.w * f.w;
  }
  s += __shfl_xor(s, 1);
  s += __shfl_xor(s, 2);
  if (part == 0) y[b * E_ + o] = s + bo[o];
}

// ---------------------------------------------------------------------------
// Kernel 4: broadcast y (B,E) to out (B,L,E).
// ---------------------------------------------------------------------------
__global__ void broadcast_out(const float* __restrict__ y,
                              float4* __restrict__ out4) {
  const size_t total = (size_t)B_ * L_ * (E_ / 4);
  const float4* y4 = (const float4*)y;
  for (size_t i = (size_t)blockIdx.x * blockDim.x + threadIdx.x; i < total;
       i += (size_t)gridDim.x * blockDim.x) {
    size_t e4 = i & (E_ / 4 - 1);
    size_t b = i >> 20;
    out4[i] = y4[b * (E_ / 4) + e4];
  }
}

// ---------------------------------------------------------------------------
extern "C" void kernel_launch(void* const* d_in, const int* in_sizes, int n_in,
                              void* d_out, int out_size, void* d_ws,
                              size_t ws_size, hipStream_t stream) {
  const float* x  = (const float*)d_in[0];
  const float* Wq = (const float*)d_in[1];
  const float* bq = (const float*)d_in[2];
  const float* Wk = (const float*)d_in[3];
  const float* bk = (const float*)d_in[4];
  const float* Wv = (const float*)d_in[5];
  const float* bv = (const float*)d_in[6];
  const float* Wo = (const float*)d_in[7];
  const float* bo = (const float*)d_in[8];

  char* w = (char*)d_ws;
  float* KT            = (float*)w;
  unsigned short* Vb   = (unsigned short*)(w + 134217728);
  unsigned short* Whi  = (unsigned short*)(w + 201326592);
  unsigned short* Wlo  = (unsigned short*)(w + 207618048);
  float2* Spart        = (float2*)(w + 213909504);
  float* flat          = (float*)(w + 230686720);
  float* y             = (float*)(w + 230719488);
  float* QT            = (float*)d_out;  // scratch; overwritten by broadcast

  conv_w<<<dim3(1024, 3), 256, 0, stream>>>(Wq, Wk, Wv, Whi, Wlo);
  qkv_gemm<<<dim3(24, 256), 256, 0, stream>>>(x, Whi, Wlo, bq, bk, bv, QT, KT, Vb);
  corr_fft<<<dim3(B_ * H_, 8), 1024, 0, stream>>>(QT, KT, Spart);
  corr_post<<<dim3(B_ * H_), 1024, 0, stream>>>(Spart, Vb, flat);
  final_proj<<<dim3(16, B_), 256, 0, stream>>>(flat, Wo, bo, y);
  broadcast_out<<<dim3(2048), 256, 0, stream>>>(y, (float4*)d_out);
}

// Round 5
// 791.812 us; speedup vs baseline: 5.4325x; 1.1373x over previous
//
#include <hip/hip_runtime.h>
#include <hip/hip_bf16.h>
#include <math.h>

// Problem constants (AutoCorrelationAttention): B=8, L=4096, E=1024, H=16, D=64
#define B_ 8
#define L_ 4096
#define E_ 1024
#define H_ 16
#define D_ 64

typedef short short8 __attribute__((ext_vector_type(8)));
typedef float f32x4 __attribute__((ext_vector_type(4)));

__device__ __forceinline__ unsigned short f2bf(float f) {
  unsigned int u = __float_as_uint(f);
  unsigned int r = u + 0x7FFFu + ((u >> 16) & 1u);
  return (unsigned short)(r >> 16);
}
__device__ __forceinline__ float bf2f(unsigned short h) {
  return __uint_as_float(((unsigned int)h) << 16);
}

#define GLDS16(g, l)                                                     \
  __builtin_amdgcn_global_load_lds(                                      \
      (const __attribute__((address_space(1))) void*)(g),                \
      (__attribute__((address_space(3))) void*)(l), 16, 0, 0)

// ---------------------------------------------------------------------------
// Kernel 0: split Wq/Wk/Wv into bf16 hi/lo, fused [3072][1024] layout.
// ---------------------------------------------------------------------------
__global__ __launch_bounds__(256) void conv_w(
    const float* __restrict__ Wq, const float* __restrict__ Wk,
    const float* __restrict__ Wv, unsigned short* __restrict__ Whi,
    unsigned short* __restrict__ Wlo) {
  const int wsel = blockIdx.y;
  const float* W = (wsel == 0) ? Wq : (wsel == 1) ? Wk : Wv;
  size_t i = ((size_t)blockIdx.x * 256 + threadIdx.x) * 4;
  float4 f = *(const float4*)(W + i);
  size_t o = (size_t)wsel * (1024 * 1024) + i;
  float ff[4] = {f.x, f.y, f.z, f.w};
  unsigned short hh[4], ll[4];
#pragma unroll
  for (int e = 0; e < 4; ++e) {
    hh[e] = f2bf(ff[e]);
    ll[e] = f2bf(ff[e] - bf2f(hh[e]));
  }
  *(ushort4*)(Whi + o) = make_ushort4(hh[0], hh[1], hh[2], hh[3]);
  *(ushort4*)(Wlo + o) = make_ushort4(ll[0], ll[1], ll[2], ll[3]);
}

// ---------------------------------------------------------------------------
// Kernel 1: fused QKV projection, 2-term split-bf16 MFMA GEMM:
//   C = round_bf16(x) @ (Whi + Wlo)^T + bias   (error ~ xlo*W ~ 2^-10 rel)
// T2 XOR-swizzled LDS tiles (16B block p = c ^ (row&7) within 128B rows):
//   - B: linear global_load_lds dest + inverse-swizzled GLOBAL source col
//   - A: reg-staged hi-rounded bf16, ds_write to swizzled block
//   - fragment ds_read_b128 at swizzled block
// LDS = 48 KB -> 3 blocks/CU.
// ---------------------------------------------------------------------------
__global__ __launch_bounds__(256) void qkv_gemm(
    const float* __restrict__ x, const unsigned short* __restrict__ Whi,
    const unsigned short* __restrict__ Wlo, const float* __restrict__ bq,
    const float* __restrict__ bk, const float* __restrict__ bv,
    float* __restrict__ QT, float* __restrict__ KT,
    unsigned short* __restrict__ Vb) {
  __shared__ unsigned short sAhi[128 * 64];
  __shared__ unsigned short sBhi[128 * 64];
  __shared__ unsigned short sBlo[128 * 64];

  const int tid = threadIdx.x;
  const int wid = tid >> 6, lane = tid & 63;
  const int n0 = blockIdx.x * 128;
  const int m0 = blockIdx.y * 128;

  f32x4 acc[4][4];
#pragma unroll
  for (int i = 0; i < 4; ++i)
#pragma unroll
    for (int j = 0; j < 4; ++j) acc[i][j] = (f32x4){0.f, 0.f, 0.f, 0.f};

  const int brow = lane >> 3;                              // row within 8-row block
  const int bcol = (((lane & 7) ^ (brow & 7)) & 7) * 8;    // swizzled source col
  const int arow = tid >> 3;                               // row within 32-row quarter
  const int acol = (tid & 7) * 8;                          // natural source col
  const int awz  = ((tid & 7) ^ (arow & 7)) * 8;           // swizzled LDS block
  const int wm = (wid >> 1) * 64, wn = (wid & 1) * 64;
  const int fr = lane & 15, fg = lane >> 4;
  const int fr7 = fr & 7;

  for (int k0 = 0; k0 < E_; k0 += 64) {
    __syncthreads();
    // ---- stage B hi/lo direct to LDS (linear dest, pre-swizzled source)
#pragma unroll
    for (int q = 0; q < 4; ++q) {
      const int rb = (wid * 4 + q) * 8;
      GLDS16(Whi + (size_t)(n0 + rb + brow) * E_ + k0 + bcol, &sBhi[rb * 64]);
      GLDS16(Wlo + (size_t)(n0 + rb + brow) * E_ + k0 + bcol, &sBlo[rb * 64]);
    }
    // ---- stage A: fp32 -> rounded bf16 (hi only), ds_write to swizzled block
#pragma unroll
    for (int q = 0; q < 4; ++q) {
      float af[8];
      const float* g = x + (size_t)(m0 + q * 32 + arow) * E_ + k0 + acol;
      *(float4*)&af[0] = *(const float4*)(g);
      *(float4*)&af[4] = *(const float4*)(g + 4);
      short8 vh;
#pragma unroll
      for (int e = 0; e < 8; ++e) vh[e] = (short)f2bf(af[e]);
      *(short8*)&sAhi[q * 2048 + arow * 64 + awz] = vh;
    }
    __syncthreads();
    // ---- compute: 2 passes (Bhi, Blo) x 32 MFMA, swizzled fragment reads
    short8 afr[4][2];
#pragma unroll
    for (int i = 0; i < 4; ++i)
#pragma unroll
      for (int kk = 0; kk < 2; ++kk) {
        const int blk = (((kk * 4 + fg) ^ fr7) << 3);
        afr[i][kk] = *(const short8*)&sAhi[(wm + i * 16 + fr) * 64 + blk];
      }
#pragma unroll
    for (int p = 0; p < 2; ++p) {
      const unsigned short* bb = (p == 0) ? sBhi : sBlo;
      short8 bfr[4][2];
#pragma unroll
      for (int j = 0; j < 4; ++j)
#pragma unroll
        for (int kk = 0; kk < 2; ++kk) {
          const int blk = (((kk * 4 + fg) ^ fr7) << 3);
          bfr[j][kk] = *(const short8*)&bb[(wn + j * 16 + fr) * 64 + blk];
        }
#pragma unroll
      for (int i = 0; i < 4; ++i)
#pragma unroll
        for (int j = 0; j < 4; ++j)
#pragma unroll
          for (int kk = 0; kk < 2; ++kk)
            acc[i][j] = __builtin_amdgcn_mfma_f32_16x16x32_bf16(
                afr[i][kk], bfr[j][kk], acc[i][j], 0, 0, 0);
    }
  }

  const int wsel = n0 >> 10;
  const float* bias = (wsel == 0) ? bq : (wsel == 1) ? bk : bv;
  float br[4];
#pragma unroll
  for (int j = 0; j < 4; ++j)
    br[j] = bias[(n0 & 1023) + wn + j * 16 + fr];

  if (wsel < 2) {
    float* T = (wsel == 0) ? QT : KT;
    const int b = m0 >> 12;
    const int lbase = (m0 & 4095) + wm + (fg << 2);
#pragma unroll
    for (int i = 0; i < 4; ++i)
#pragma unroll
      for (int j = 0; j < 4; ++j) {
        const int n_in = (n0 & 1023) + wn + j * 16 + fr;
        float4 v = make_float4(acc[i][j][0] + br[j], acc[i][j][1] + br[j],
                               acc[i][j][2] + br[j], acc[i][j][3] + br[j]);
        *(float4*)&T[((size_t)(b << 10) + n_in) * L_ + lbase + i * 16] = v;
      }
  } else {
#pragma unroll
    for (int i = 0; i < 4; ++i)
#pragma unroll
      for (int j = 0; j < 4; ++j) {
        const int n_in = (n0 & 1023) + wn + j * 16 + fr;
#pragma unroll
        for (int r = 0; r < 4; ++r) {
          const int m = m0 + wm + i * 16 + (fg << 2) + r;
          Vb[(size_t)m * E_ + n_in] = f2bf(acc[i][j][r] + br[j]);
        }
      }
  }
}

// ---------------------------------------------------------------------------
// In-LDS Stockham radix-4 FFT, N=4096, 1024 threads: one butterfly per
// thread per stage, 6 stages, result in A.
// ---------------------------------------------------------------------------
__device__ __forceinline__ float2 cmulf(float2 a, float2 b) {
  return make_float2(a.x * b.x - a.y * b.y, a.x * b.y + a.y * b.x);
}

__device__ __forceinline__ void fft4096_1024(float2* __restrict__ A,
                                             float2* __restrict__ Bb,
                                             int tid, float sign) {
  float2* cur = A;
  float2* nxt = Bb;
  const float TWO_PI = 6.28318530717958647692f;
#pragma unroll
  for (int st = 0; st < 6; ++st) {
    const int Ns = 1 << (2 * st);
    __syncthreads();
    const int j = tid;
    float2 v0 = cur[j];
    float2 v1 = cur[j + 1024];
    float2 v2 = cur[j + 2048];
    float2 v3 = cur[j + 3072];
    const int r = j & (Ns - 1);
    float ang = sign * TWO_PI * (float)r / (float)(4 * Ns);
    float s1, c1;
    __sincosf(ang, &s1, &c1);
    float2 w1 = make_float2(c1, s1);
    float2 w2 = cmulf(w1, w1);
    float2 w3 = cmulf(w2, w1);
    v1 = cmulf(v1, w1);
    v2 = cmulf(v2, w2);
    v3 = cmulf(v3, w3);
    float2 t0 = make_float2(v0.x + v2.x, v0.y + v2.y);
    float2 t1 = make_float2(v0.x - v2.x, v0.y - v2.y);
    float2 t2 = make_float2(v1.x + v3.x, v1.y + v3.y);
    float2 t3 = make_float2(v1.x - v3.x, v1.y - v3.y);
    float2 t3i = make_float2(-sign * t3.y, sign * t3.x);
    const int idxD = ((j - r) << 2) + r;
    nxt[idxD]          = make_float2(t0.x + t2.x, t0.y + t2.y);
    nxt[idxD + Ns]     = make_float2(t1.x + t3i.x, t1.y + t3i.y);
    nxt[idxD + 2 * Ns] = make_float2(t0.x - t2.x, t0.y - t2.y);
    nxt[idxD + 3 * Ns] = make_float2(t1.x - t3i.x, t1.y - t3i.y);
    float2* tmp = cur; cur = nxt; nxt = tmp;
  }
  __syncthreads();
}

// ---------------------------------------------------------------------------
// Kernel 2a: per-(b,h,ds) partial cross-spectrum. 8 packed FFTs per block.
// ---------------------------------------------------------------------------
__global__ __launch_bounds__(1024) void corr_fft(
    const float* __restrict__ QT, const float* __restrict__ KT,
    float2* __restrict__ Spart) {
  __shared__ float2 bufA[L_];      // 32 KB
  __shared__ float2 bufB[L_];      // 32 KB
  __shared__ float2 S[L_ / 2];     // 16 KB (Nyquist packed into S[0].y)

  const int bh = blockIdx.x, ds = blockIdx.y;
  const int b = bh >> 4, h = bh & (H_ - 1);
  const int tid = threadIdx.x;

  for (int f = tid; f < L_ / 2; f += 1024) S[f] = make_float2(0.f, 0.f);

  const size_t baseQK = (size_t)(b * E_ + h * D_) * L_;

  for (int dd = 0; dd < 8; ++dd) {
    const int d = ds * 8 + dd;
    __syncthreads();
    const float* q = QT + baseQK + (size_t)d * L_;
    const float* k = KT + baseQK + (size_t)d * L_;
    float4 q4 = *(const float4*)(q + tid * 4);
    float4 k4 = *(const float4*)(k + tid * 4);
    *(float4*)&bufA[tid * 4]     = make_float4(q4.x, k4.x, q4.y, k4.y);
    *(float4*)&bufA[tid * 4 + 2] = make_float4(q4.z, k4.z, q4.w, k4.w);
    fft4096_1024(bufA, bufB, tid, -1.0f);
    for (int f = tid; f <= L_ / 2; f += 1024) {
      float2 Zf = bufA[f];
      float2 Zc = bufA[(L_ - f) & (L_ - 1)];
      float ax = Zc.x, ay = -Zc.y;
      float qx = 0.5f * (Zf.x + ax), qy = 0.5f * (Zf.y + ay);
      float ux = Zf.x - ax, uy = Zf.y - ay;
      float kx = 0.5f * uy, ky = -0.5f * ux;
      float re = qx * kx + qy * ky;
      float im = qy * kx - qx * ky;
      if (f == 0) S[0].x += re;
      else if (f == L_ / 2) S[0].y += re;
      else { S[f].x += re; S[f].y += im; }
    }
  }
  __syncthreads();
  float2* out = Spart + (size_t)(bh * 8 + ds) * (L_ / 2);
  for (int f = tid; f < L_ / 2; f += 1024) out[f] = S[f];
}

// ---------------------------------------------------------------------------
// Kernel 2b: per-(b,h) reduce partials -> inverse FFT -> softmax -> attn@V.
// ---------------------------------------------------------------------------
__global__ __launch_bounds__(1024) void corr_post(
    const float2* __restrict__ Spart, const unsigned short* __restrict__ Vb,
    float* __restrict__ out_flat) {
  __shared__ float2 bufA[L_];
  __shared__ float2 bufB[L_];
  __shared__ float red[1024];

  const int bh = blockIdx.x;
  const int b = bh >> 4, h = bh & (H_ - 1);
  const int tid = threadIdx.x;

  const float2* sp = Spart + (size_t)(bh * 8) * (L_ / 2);
  for (int f = tid; f < L_ / 2; f += 1024) {
    float2 s = make_float2(0.f, 0.f);
#pragma unroll
    for (int ds = 0; ds < 8; ++ds) {
      float2 p = sp[(size_t)ds * (L_ / 2) + f];
      s.x += p.x;
      s.y += p.y;
    }
    if (f == 0) {
      bufA[0] = make_float2(s.x, 0.f);
      bufA[L_ / 2] = make_float2(s.y, 0.f);
    } else {
      bufA[f] = s;
      bufA[L_ - f] = make_float2(s.x, -s.y);
    }
  }
  fft4096_1024(bufA, bufB, tid, 1.0f);

  const float cscale = 1.0f / ((float)L_ * (float)D_);
  float lmax = -3.0e38f;
#pragma unroll
  for (int q = 0; q < 4; ++q) lmax = fmaxf(lmax, bufA[tid + q * 1024].x);
  red[tid] = lmax;
  __syncthreads();
  for (int s = 512; s > 0; s >>= 1) {
    if (tid < s) red[tid] = fmaxf(red[tid], red[tid + s]);
    __syncthreads();
  }
  const float gmax = red[0] * cscale;
  __syncthreads();
  float lsum = 0.f;
#pragma unroll
  for (int q = 0; q < 4; ++q) {
    float w = __expf(bufA[tid + q * 1024].x * cscale - gmax);
    bufA[tid + q * 1024].x = w;
    lsum += w;
  }
  red[tid] = lsum;
  __syncthreads();
  for (int s = 512; s > 0; s >>= 1) {
    if (tid < s) red[tid] += red[tid + s];
    __syncthreads();
  }
  const float inv = 1.0f / red[0];
  __syncthreads();

  const int d = tid & 63, g = tid >> 6;
  const unsigned short* vb = Vb + (size_t)b * L_ * E_ + h * D_ + d;
  float acc = 0.f;
  for (int l = g; l < L_; l += 16)
    acc = fmaf(bufA[l].x, bf2f(vb[(size_t)l * E_]), acc);
  red[tid] = acc;
  __syncthreads();
  if (tid < 64) {
    float t = 0.f;
#pragma unroll
    for (int g2 = 0; g2 < 16; ++g2) t += red[g2 * 64 + tid];
    out_flat[b * E_ + tid * H_ + h] = t * inv;
  }
}

// ---------------------------------------------------------------------------
// Kernel 3: y[b,o] = bo[o] + sum_j flat[b,j] * Wo[o,j]  (128 blocks)
// ---------------------------------------------------------------------------
__global__ __launch_bounds__(256) void final_proj(
    const float* __restrict__ flat, const float* __restrict__ Wo,
    const float* __restrict__ bo, float* __restrict__ y) {
  __shared__ float sf[E_];
  const int b = blockIdx.y;
  const int o0 = blockIdx.x * 64;
  for (int j = threadIdx.x; j < E_; j += 256) sf[j] = flat[b * E_ + j];
  __syncthreads();
  const int oo = threadIdx.x >> 2, part = threadIdx.x & 3;
  const int o = o0 + oo;
  const float4* wr = (const float4*)(Wo + (size_t)o * E_) + part * 64;
  const float4* fr = (const float4*)sf + part * 64;
  float s = 0.f;
#pragma unroll 8
  for (int i = 0; i < 64; ++i) {
    float4 w = wr[i];
    float4 f = fr[i];
    s += w.x * f.x + w.y * f.y + w.z * f.z + w.w * f.w;
  }
  s += __shfl_xor(s, 1);
  s += __shfl_xor(s, 2);
  if (part == 0) y[b * E_ + o] = s + bo[o];
}

// ---------------------------------------------------------------------------
// Kernel 4: broadcast y (B,E) to out (B,L,E).
// ---------------------------------------------------------------------------
__global__ void broadcast_out(const float* __restrict__ y,
                              float4* __restrict__ out4) {
  const size_t total = (size_t)B_ * L_ * (E_ / 4);
  const float4* y4 = (const float4*)y;
  for (size_t i = (size_t)blockIdx.x * blockDim.x + threadIdx.x; i < total;
       i += (size_t)gridDim.x * blockDim.x) {
    size_t e4 = i & (E_ / 4 - 1);
    size_t b = i >> 20;
    out4[i] = y4[b * (E_ / 4) + e4];
  }
}

// ---------------------------------------------------------------------------
extern "C" void kernel_launch(void* const* d_in, const int* in_sizes, int n_in,
                              void* d_out, int out_size, void* d_ws,
                              size_t ws_size, hipStream_t stream) {
  const float* x  = (const float*)d_in[0];
  const float* Wq = (const float*)d_in[1];
  const float* bq = (const float*)d_in[2];
  const float* Wk = (const float*)d_in[3];
  const float* bk = (const float*)d_in[4];
  const float* Wv = (const float*)d_in[5];
  const float* bv = (const float*)d_in[6];
  const float* Wo = (const float*)d_in[7];
  const float* bo = (const float*)d_in[8];

  char* w = (char*)d_ws;
  float* KT            = (float*)w;
  unsigned short* Vb   = (unsigned short*)(w + 134217728);
  unsigned short* Whi  = (unsigned short*)(w + 201326592);
  unsigned short* Wlo  = (unsigned short*)(w + 207618048);
  float2* Spart        = (float2*)(w + 213909504);
  float* flat          = (float*)(w + 230686720);
  float* y             = (float*)(w + 230719488);
  float* QT            = (float*)d_out;  // scratch; overwritten by broadcast

  conv_w<<<dim3(1024, 3), 256, 0, stream>>>(Wq, Wk, Wv, Whi, Wlo);
  qkv_gemm<<<dim3(24, 256), 256, 0, stream>>>(x, Whi, Wlo, bq, bk, bv, QT, KT, Vb);
  corr_fft<<<dim3(B_ * H_, 8), 1024, 0, stream>>>(QT, KT, Spart);
  corr_post<<<dim3(B_ * H_), 1024, 0, stream>>>(Spart, Vb, flat);
  final_proj<<<dim3(16, B_), 256, 0, stream>>>(flat, Wo, bo, y);
  broadcast_out<<<dim3(2048), 256, 0, stream>>>(y, (float4*)d_out);
}

// Round 6
// 693.950 us; speedup vs baseline: 6.1986x; 1.1410x over previous
//
#include <hip/hip_runtime.h>
#include <hip/hip_bf16.h>
#include <math.h>

// Problem constants (AutoCorrelationAttention): B=8, L=4096, E=1024, H=16, D=64
#define B_ 8
#define L_ 4096
#define E_ 1024
#define H_ 16
#define D_ 64

typedef short short8 __attribute__((ext_vector_type(8)));
typedef float f32x4 __attribute__((ext_vector_type(4)));

__device__ __forceinline__ unsigned short f2bf(float f) {
  unsigned int u = __float_as_uint(f);
  unsigned int r = u + 0x7FFFu + ((u >> 16) & 1u);
  return (unsigned short)(r >> 16);
}
__device__ __forceinline__ float bf2f(unsigned short h) {
  return __uint_as_float(((unsigned int)h) << 16);
}

#define GLDS16(g, l)                                                     \
  __builtin_amdgcn_global_load_lds(                                      \
      (const __attribute__((address_space(1))) void*)(g),                \
      (__attribute__((address_space(3))) void*)(l), 16, 0, 0)

// ---------------------------------------------------------------------------
// Kernel 0a: split Wq/Wk/Wv into bf16 hi/lo, fused [3072][1024] layout.
// ---------------------------------------------------------------------------
__global__ __launch_bounds__(256) void conv_w(
    const float* __restrict__ Wq, const float* __restrict__ Wk,
    const float* __restrict__ Wv, unsigned short* __restrict__ Whi,
    unsigned short* __restrict__ Wlo) {
  const int wsel = blockIdx.y;
  const float* W = (wsel == 0) ? Wq : (wsel == 1) ? Wk : Wv;
  size_t i = ((size_t)blockIdx.x * 256 + threadIdx.x) * 4;
  float4 f = *(const float4*)(W + i);
  size_t o = (size_t)wsel * (1024 * 1024) + i;
  float ff[4] = {f.x, f.y, f.z, f.w};
  unsigned short hh[4], ll[4];
#pragma unroll
  for (int e = 0; e < 4; ++e) {
    hh[e] = f2bf(ff[e]);
    ll[e] = f2bf(ff[e] - bf2f(hh[e]));
  }
  *(ushort4*)(Whi + o) = make_ushort4(hh[0], hh[1], hh[2], hh[3]);
  *(ushort4*)(Wlo + o) = make_ushort4(ll[0], ll[1], ll[2], ll[3]);
}

// ---------------------------------------------------------------------------
// Kernel 0b: convert x (fp32) -> xb (bf16, rounded), natural layout.
// ---------------------------------------------------------------------------
__global__ __launch_bounds__(256) void conv_x(const float* __restrict__ x,
                                              unsigned short* __restrict__ xb) {
  const size_t total = (size_t)B_ * L_ * E_ / 8;  // threads-worth of 8 els
  for (size_t i = (size_t)blockIdx.x * blockDim.x + threadIdx.x; i < total;
       i += (size_t)gridDim.x * blockDim.x) {
    float4 a = ((const float4*)x)[i * 2];
    float4 b = ((const float4*)x)[i * 2 + 1];
    short8 v;
    v[0] = (short)f2bf(a.x); v[1] = (short)f2bf(a.y);
    v[2] = (short)f2bf(a.z); v[3] = (short)f2bf(a.w);
    v[4] = (short)f2bf(b.x); v[5] = (short)f2bf(b.y);
    v[6] = (short)f2bf(b.z); v[7] = (short)f2bf(b.w);
    *(short8*)&xb[i * 8] = v;
  }
}

// ---------------------------------------------------------------------------
// Kernel 1: fused QKV projection, 2-term split-bf16 MFMA GEMM:
//   C = xb @ (Whi + Wlo)^T + bias
// All three tiles (A, Bhi, Blo) staged via global_load_lds width=16 with
// T2 pre-swizzled global source (16B block p = c ^ (row&7) in 128B rows).
// No ds_writes, no in-loop conversion. LDS = 48 KB.
// Epilogue: Q,K -> transposed bf16 (B,E,L); V -> natural bf16 (B,L,E).
// ---------------------------------------------------------------------------
__global__ __launch_bounds__(256) void qkv_gemm(
    const unsigned short* __restrict__ xb,
    const unsigned short* __restrict__ Whi,
    const unsigned short* __restrict__ Wlo, const float* __restrict__ bq,
    const float* __restrict__ bk, const float* __restrict__ bv,
    unsigned short* __restrict__ QTb, unsigned short* __restrict__ KTb,
    unsigned short* __restrict__ Vb) {
  __shared__ unsigned short sA[128 * 64];
  __shared__ unsigned short sBhi[128 * 64];
  __shared__ unsigned short sBlo[128 * 64];

  const int tid = threadIdx.x;
  const int wid = tid >> 6, lane = tid & 63;
  const int n0 = blockIdx.x * 128;
  const int m0 = blockIdx.y * 128;

  f32x4 acc[4][4];
#pragma unroll
  for (int i = 0; i < 4; ++i)
#pragma unroll
    for (int j = 0; j < 4; ++j) acc[i][j] = (f32x4){0.f, 0.f, 0.f, 0.f};

  const int brow = lane >> 3;                              // row within 8-row issue
  const int bcol = (((lane & 7) ^ (brow & 7)) & 7) * 8;    // swizzled source col
  const int wm = (wid >> 1) * 64, wn = (wid & 1) * 64;
  const int fr = lane & 15, fg = lane >> 4;
  const int fr7 = fr & 7;

  for (int k0 = 0; k0 < E_; k0 += 64) {
    __syncthreads();
    // ---- stage A, Bhi, Blo direct to LDS (linear dest, pre-swizzled src)
#pragma unroll
    for (int q = 0; q < 4; ++q) {
      const int rb = (wid * 4 + q) * 8;
      GLDS16(xb  + (size_t)(m0 + rb + brow) * E_ + k0 + bcol, &sA[rb * 64]);
      GLDS16(Whi + (size_t)(n0 + rb + brow) * E_ + k0 + bcol, &sBhi[rb * 64]);
      GLDS16(Wlo + (size_t)(n0 + rb + brow) * E_ + k0 + bcol, &sBlo[rb * 64]);
    }
    __syncthreads();
    // ---- compute: 2 passes (Bhi, Blo) x 32 MFMA, swizzled fragment reads
    short8 afr[4][2];
#pragma unroll
    for (int i = 0; i < 4; ++i)
#pragma unroll
      for (int kk = 0; kk < 2; ++kk) {
        const int blk = (((kk * 4 + fg) ^ fr7) << 3);
        afr[i][kk] = *(const short8*)&sA[(wm + i * 16 + fr) * 64 + blk];
      }
#pragma unroll
    for (int p = 0; p < 2; ++p) {
      const unsigned short* bb = (p == 0) ? sBhi : sBlo;
      short8 bfr[4][2];
#pragma unroll
      for (int j = 0; j < 4; ++j)
#pragma unroll
        for (int kk = 0; kk < 2; ++kk) {
          const int blk = (((kk * 4 + fg) ^ fr7) << 3);
          bfr[j][kk] = *(const short8*)&bb[(wn + j * 16 + fr) * 64 + blk];
        }
#pragma unroll
      for (int i = 0; i < 4; ++i)
#pragma unroll
        for (int j = 0; j < 4; ++j)
#pragma unroll
          for (int kk = 0; kk < 2; ++kk)
            acc[i][j] = __builtin_amdgcn_mfma_f32_16x16x32_bf16(
                afr[i][kk], bfr[j][kk], acc[i][j], 0, 0, 0);
    }
  }

  const int wsel = n0 >> 10;
  const float* bias = (wsel == 0) ? bq : (wsel == 1) ? bk : bv;
  float br[4];
#pragma unroll
  for (int j = 0; j < 4; ++j)
    br[j] = bias[(n0 & 1023) + wn + j * 16 + fr];

  if (wsel < 2) {
    unsigned short* T = (wsel == 0) ? QTb : KTb;
    const int b = m0 >> 12;
    const int lbase = (m0 & 4095) + wm + (fg << 2);
#pragma unroll
    for (int i = 0; i < 4; ++i)
#pragma unroll
      for (int j = 0; j < 4; ++j) {
        const int n_in = (n0 & 1023) + wn + j * 16 + fr;
        ushort4 v = make_ushort4(f2bf(acc[i][j][0] + br[j]),
                                 f2bf(acc[i][j][1] + br[j]),
                                 f2bf(acc[i][j][2] + br[j]),
                                 f2bf(acc[i][j][3] + br[j]));
        *(ushort4*)&T[((size_t)(b << 10) + n_in) * L_ + lbase + i * 16] = v;
      }
  } else {
#pragma unroll
    for (int i = 0; i < 4; ++i)
#pragma unroll
      for (int j = 0; j < 4; ++j) {
        const int n_in = (n0 & 1023) + wn + j * 16 + fr;
#pragma unroll
        for (int r = 0; r < 4; ++r) {
          const int m = m0 + wm + i * 16 + (fg << 2) + r;
          Vb[(size_t)m * E_ + n_in] = f2bf(acc[i][j][r] + br[j]);
        }
      }
  }
}

// ---------------------------------------------------------------------------
// In-LDS Stockham radix-4 FFT, N=4096, 1024 threads: one butterfly per
// thread per stage, 6 stages, result in A.
// ---------------------------------------------------------------------------
__device__ __forceinline__ float2 cmulf(float2 a, float2 b) {
  return make_float2(a.x * b.x - a.y * b.y, a.x * b.y + a.y * b.x);
}

__device__ __forceinline__ void fft4096_1024(float2* __restrict__ A,
                                             float2* __restrict__ Bb,
                                             int tid, float sign) {
  float2* cur = A;
  float2* nxt = Bb;
  const float TWO_PI = 6.28318530717958647692f;
#pragma unroll
  for (int st = 0; st < 6; ++st) {
    const int Ns = 1 << (2 * st);
    __syncthreads();
    const int j = tid;
    float2 v0 = cur[j];
    float2 v1 = cur[j + 1024];
    float2 v2 = cur[j + 2048];
    float2 v3 = cur[j + 3072];
    const int r = j & (Ns - 1);
    float ang = sign * TWO_PI * (float)r / (float)(4 * Ns);
    float s1, c1;
    __sincosf(ang, &s1, &c1);
    float2 w1 = make_float2(c1, s1);
    float2 w2 = cmulf(w1, w1);
    float2 w3 = cmulf(w2, w1);
    v1 = cmulf(v1, w1);
    v2 = cmulf(v2, w2);
    v3 = cmulf(v3, w3);
    float2 t0 = make_float2(v0.x + v2.x, v0.y + v2.y);
    float2 t1 = make_float2(v0.x - v2.x, v0.y - v2.y);
    float2 t2 = make_float2(v1.x + v3.x, v1.y + v3.y);
    float2 t3 = make_float2(v1.x - v3.x, v1.y - v3.y);
    float2 t3i = make_float2(-sign * t3.y, sign * t3.x);
    const int idxD = ((j - r) << 2) + r;
    nxt[idxD]          = make_float2(t0.x + t2.x, t0.y + t2.y);
    nxt[idxD + Ns]     = make_float2(t1.x + t3i.x, t1.y + t3i.y);
    nxt[idxD + 2 * Ns] = make_float2(t0.x - t2.x, t0.y - t2.y);
    nxt[idxD + 3 * Ns] = make_float2(t1.x - t3i.x, t1.y - t3i.y);
    float2* tmp = cur; cur = nxt; nxt = tmp;
  }
  __syncthreads();
}

// ---------------------------------------------------------------------------
// Kernel 2a: per-(b,h,ds) partial cross-spectrum. 8 packed FFTs per block.
// ---------------------------------------------------------------------------
__global__ __launch_bounds__(1024) void corr_fft(
    const unsigned short* __restrict__ QTb,
    const unsigned short* __restrict__ KTb, float2* __restrict__ Spart) {
  __shared__ float2 bufA[L_];      // 32 KB
  __shared__ float2 bufB[L_];      // 32 KB
  __shared__ float2 S[L_ / 2];     // 16 KB (Nyquist packed into S[0].y)

  const int bh = blockIdx.x, ds = blockIdx.y;
  const int b = bh >> 4, h = bh & (H_ - 1);
  const int tid = threadIdx.x;

  for (int f = tid; f < L_ / 2; f += 1024) S[f] = make_float2(0.f, 0.f);

  const size_t baseQK = (size_t)(b * E_ + h * D_) * L_;

  for (int dd = 0; dd < 8; ++dd) {
    const int d = ds * 8 + dd;
    __syncthreads();
    const unsigned short* q = QTb + baseQK + (size_t)d * L_;
    const unsigned short* k = KTb + baseQK + (size_t)d * L_;
    ushort4 q4 = *(const ushort4*)(q + tid * 4);
    ushort4 k4 = *(const ushort4*)(k + tid * 4);
    bufA[tid * 4 + 0] = make_float2(bf2f(q4.x), bf2f(k4.x));
    bufA[tid * 4 + 1] = make_float2(bf2f(q4.y), bf2f(k4.y));
    bufA[tid * 4 + 2] = make_float2(bf2f(q4.z), bf2f(k4.z));
    bufA[tid * 4 + 3] = make_float2(bf2f(q4.w), bf2f(k4.w));
    fft4096_1024(bufA, bufB, tid, -1.0f);
    for (int f = tid; f <= L_ / 2; f += 1024) {
      float2 Zf = bufA[f];
      float2 Zc = bufA[(L_ - f) & (L_ - 1)];
      float ax = Zc.x, ay = -Zc.y;
      float qx = 0.5f * (Zf.x + ax), qy = 0.5f * (Zf.y + ay);
      float ux = Zf.x - ax, uy = Zf.y - ay;
      float kx = 0.5f * uy, ky = -0.5f * ux;
      float re = qx * kx + qy * ky;
      float im = qy * kx - qx * ky;
      if (f == 0) S[0].x += re;
      else if (f == L_ / 2) S[0].y += re;
      else { S[f].x += re; S[f].y += im; }
    }
  }
  __syncthreads();
  float2* out = Spart + (size_t)(bh * 8 + ds) * (L_ / 2);
  for (int f = tid; f < L_ / 2; f += 1024) out[f] = S[f];
}

// ---------------------------------------------------------------------------
// Kernel 2b: per-(b,h) reduce partials -> inverse FFT -> softmax -> attn@V.
// ---------------------------------------------------------------------------
__global__ __launch_bounds__(1024) void corr_post(
    const float2* __restrict__ Spart, const unsigned short* __restrict__ Vb,
    float* __restrict__ out_flat) {
  __shared__ float2 bufA[L_];
  __shared__ float2 bufB[L_];
  __shared__ float red[1024];

  const int bh = blockIdx.x;
  const int b = bh >> 4, h = bh & (H_ - 1);
  const int tid = threadIdx.x;

  const float2* sp = Spart + (size_t)(bh * 8) * (L_ / 2);
  for (int f = tid; f < L_ / 2; f += 1024) {
    float2 s = make_float2(0.f, 0.f);
#pragma unroll
    for (int ds = 0; ds < 8; ++ds) {
      float2 p = sp[(size_t)ds * (L_ / 2) + f];
      s.x += p.x;
      s.y += p.y;
    }
    if (f == 0) {
      bufA[0] = make_float2(s.x, 0.f);
      bufA[L_ / 2] = make_float2(s.y, 0.f);
    } else {
      bufA[f] = s;
      bufA[L_ - f] = make_float2(s.x, -s.y);
    }
  }
  fft4096_1024(bufA, bufB, tid, 1.0f);

  const float cscale = 1.0f / ((float)L_ * (float)D_);
  float lmax = -3.0e38f;
#pragma unroll
  for (int q = 0; q < 4; ++q) lmax = fmaxf(lmax, bufA[tid + q * 1024].x);
  red[tid] = lmax;
  __syncthreads();
  for (int s = 512; s > 0; s >>= 1) {
    if (tid < s) red[tid] = fmaxf(red[tid], red[tid + s]);
    __syncthreads();
  }
  const float gmax = red[0] * cscale;
  __syncthreads();
  float lsum = 0.f;
#pragma unroll
  for (int q = 0; q < 4; ++q) {
    float w = __expf(bufA[tid + q * 1024].x * cscale - gmax);
    bufA[tid + q * 1024].x = w;
    lsum += w;
  }
  red[tid] = lsum;
  __syncthreads();
  for (int s = 512; s > 0; s >>= 1) {
    if (tid < s) red[tid] += red[tid + s];
    __syncthreads();
  }
  const float inv = 1.0f / red[0];
  __syncthreads();

  const int d = tid & 63, g = tid >> 6;
  const unsigned short* vb = Vb + (size_t)b * L_ * E_ + h * D_ + d;
  float acc = 0.f;
  for (int l = g; l < L_; l += 16)
    acc = fmaf(bufA[l].x, bf2f(vb[(size_t)l * E_]), acc);
  red[tid] = acc;
  __syncthreads();
  if (tid < 64) {
    float t = 0.f;
#pragma unroll
    for (int g2 = 0; g2 < 16; ++g2) t += red[g2 * 64 + tid];
    out_flat[b * E_ + tid * H_ + h] = t * inv;
  }
}

// ---------------------------------------------------------------------------
// Kernel 3: y[b,o] = bo[o] + sum_j flat[b,j] * Wo[o,j]  (128 blocks)
// ---------------------------------------------------------------------------
__global__ __launch_bounds__(256) void final_proj(
    const float* __restrict__ flat, const float* __restrict__ Wo,
    const float* __restrict__ bo, float* __restrict__ y) {
  __shared__ float sf[E_];
  const int b = blockIdx.y;
  const int o0 = blockIdx.x * 64;
  for (int j = threadIdx.x; j < E_; j += 256) sf[j] = flat[b * E_ + j];
  __syncthreads();
  const int oo = threadIdx.x >> 2, part = threadIdx.x & 3;
  const int o = o0 + oo;
  const float4* wr = (const float4*)(Wo + (size_t)o * E_) + part * 64;
  const float4* fr = (const float4*)sf + part * 64;
  float s = 0.f;
#pragma unroll 8
  for (int i = 0; i < 64; ++i) {
    float4 w = wr[i];
    float4 f = fr[i];
    s += w.x * f.x + w.y * f.y + w.z * f.z + w.w * f.w;
  }
  s += __shfl_xor(s, 1);
  s += __shfl_xor(s, 2);
  if (part == 0) y[b * E_ + o] = s + bo[o];
}

// ---------------------------------------------------------------------------
// Kernel 4: broadcast y (B,E) to out (B,L,E).
// ---------------------------------------------------------------------------
__global__ void broadcast_out(const float* __restrict__ y,
                              float4* __restrict__ out4) {
  const size_t total = (size_t)B_ * L_ * (E_ / 4);
  const float4* y4 = (const float4*)y;
  for (size_t i = (size_t)blockIdx.x * blockDim.x + threadIdx.x; i < total;
       i += (size_t)gridDim.x * blockDim.x) {
    size_t e4 = i & (E_ / 4 - 1);
    size_t b = i >> 20;
    out4[i] = y4[b * (E_ / 4) + e4];
  }
}

// ---------------------------------------------------------------------------
extern "C" void kernel_launch(void* const* d_in, const int* in_sizes, int n_in,
                              void* d_out, int out_size, void* d_ws,
                              size_t ws_size, hipStream_t stream) {
  const float* x  = (const float*)d_in[0];
  const float* Wq = (const float*)d_in[1];
  const float* bq = (const float*)d_in[2];
  const float* Wk = (const float*)d_in[3];
  const float* bk = (const float*)d_in[4];
  const float* Wv = (const float*)d_in[5];
  const float* bv = (const float*)d_in[6];
  const float* Wo = (const float*)d_in[7];
  const float* bo = (const float*)d_in[8];

  // ws layout (bytes):
  //   KTb bf16  @ 0          (67108864)
  //   Vb  bf16  @ 67108864   (67108864)
  //   Whi bf16  @ 134217728  (6291456)
  //   Wlo bf16  @ 140509184  (6291456)
  //   Spart     @ 146800640  (16777216)
  //   flat      @ 163577856  (32768)
  //   y         @ 163610624  (32768)     => ~163.6 MB
  char* w = (char*)d_ws;
  unsigned short* KTb  = (unsigned short*)w;
  unsigned short* Vb   = (unsigned short*)(w + 67108864);
  unsigned short* Whi  = (unsigned short*)(w + 134217728);
  unsigned short* Wlo  = (unsigned short*)(w + 140509184);
  float2* Spart        = (float2*)(w + 146800640);
  float* flat          = (float*)(w + 163577856);
  float* y             = (float*)(w + 163610624);
  // d_out (134.2 MB) doubles as scratch: QTb bf16 [0:67MB), xb bf16 [67:134MB)
  unsigned short* QTb  = (unsigned short*)d_out;
  unsigned short* xb   = (unsigned short*)((char*)d_out + 67108864);

  conv_w<<<dim3(1024, 3), 256, 0, stream>>>(Wq, Wk, Wv, Whi, Wlo);
  conv_x<<<dim3(2048), 256, 0, stream>>>(x, xb);
  qkv_gemm<<<dim3(24, 256), 256, 0, stream>>>(xb, Whi, Wlo, bq, bk, bv, QTb,
                                              KTb, Vb);
  corr_fft<<<dim3(B_ * H_, 8), 1024, 0, stream>>>(QTb, KTb, Spart);
  corr_post<<<dim3(B_ * H_), 1024, 0, stream>>>(Spart, Vb, flat);
  final_proj<<<dim3(16, B_), 256, 0, stream>>>(flat, Wo, bo, y);
  broadcast_out<<<dim3(2048), 256, 0, stream>>>(y, (float4*)d_out);
}

// Round 7
// 589.962 us; speedup vs baseline: 7.2912x; 1.1763x over previous
//
#include <hip/hip_runtime.h>
#include <hip/hip_bf16.h>
#include <math.h>

// Problem constants (AutoCorrelationAttention): B=8, L=4096, E=1024, H=16, D=64
#define B_ 8
#define L_ 4096
#define E_ 1024
#define H_ 16
#define D_ 64

typedef short short8 __attribute__((ext_vector_type(8)));
typedef float f32x4 __attribute__((ext_vector_type(4)));

__device__ __forceinline__ unsigned short f2bf(float f) {
  unsigned int u = __float_as_uint(f);
  unsigned int r = u + 0x7FFFu + ((u >> 16) & 1u);
  return (unsigned short)(r >> 16);
}
__device__ __forceinline__ float bf2f(unsigned short h) {
  return __uint_as_float(((unsigned int)h) << 16);
}

#define GLDS16(g, l)                                                     \
  __builtin_amdgcn_global_load_lds(                                      \
      (const __attribute__((address_space(1))) void*)(g),                \
      (__attribute__((address_space(3))) void*)(l), 16, 0, 0)

// ---------------------------------------------------------------------------
// Kernel 0a: convert Wq/Wk/Wv to bf16 (rounded), fused [3072][1024] layout.
// ---------------------------------------------------------------------------
__global__ __launch_bounds__(256) void conv_w(
    const float* __restrict__ Wq, const float* __restrict__ Wk,
    const float* __restrict__ Wv, unsigned short* __restrict__ Wb) {
  const int wsel = blockIdx.y;
  const float* W = (wsel == 0) ? Wq : (wsel == 1) ? Wk : Wv;
  size_t i = ((size_t)blockIdx.x * 256 + threadIdx.x) * 4;
  float4 f = *(const float4*)(W + i);
  size_t o = (size_t)wsel * (1024 * 1024) + i;
  *(ushort4*)(Wb + o) =
      make_ushort4(f2bf(f.x), f2bf(f.y), f2bf(f.z), f2bf(f.w));
}

// ---------------------------------------------------------------------------
// Kernel 0b: convert x (fp32) -> xb (bf16, rounded), natural layout.
// ---------------------------------------------------------------------------
__global__ __launch_bounds__(256) void conv_x(const float* __restrict__ x,
                                              unsigned short* __restrict__ xb) {
  const size_t total = (size_t)B_ * L_ * E_ / 8;
  for (size_t i = (size_t)blockIdx.x * blockDim.x + threadIdx.x; i < total;
       i += (size_t)gridDim.x * blockDim.x) {
    float4 a = ((const float4*)x)[i * 2];
    float4 b = ((const float4*)x)[i * 2 + 1];
    short8 v;
    v[0] = (short)f2bf(a.x); v[1] = (short)f2bf(a.y);
    v[2] = (short)f2bf(a.z); v[3] = (short)f2bf(a.w);
    v[4] = (short)f2bf(b.x); v[5] = (short)f2bf(b.y);
    v[6] = (short)f2bf(b.z); v[7] = (short)f2bf(b.w);
    *(short8*)&xb[i * 8] = v;
  }
}

// ---------------------------------------------------------------------------
// Kernel 1: fused QKV projection, bf16 MFMA GEMM:  C = xb @ Wb^T + bias
// A, B staged via global_load_lds width=16 with T2 pre-swizzled global
// source (16B block p = c ^ (row&7) in 128B rows). LDS = 32 KB.
// Epilogue: Q,K -> transposed bf16 (B,E,L); V -> natural bf16 (B,L,E).
// ---------------------------------------------------------------------------
__global__ __launch_bounds__(256) void qkv_gemm(
    const unsigned short* __restrict__ xb,
    const unsigned short* __restrict__ Wb, const float* __restrict__ bq,
    const float* __restrict__ bk, const float* __restrict__ bv,
    unsigned short* __restrict__ QTb, unsigned short* __restrict__ KTb,
    unsigned short* __restrict__ Vb) {
  __shared__ unsigned short sA[128 * 64];
  __shared__ unsigned short sB[128 * 64];

  const int tid = threadIdx.x;
  const int wid = tid >> 6, lane = tid & 63;
  const int n0 = blockIdx.x * 128;
  const int m0 = blockIdx.y * 128;

  f32x4 acc[4][4];
#pragma unroll
  for (int i = 0; i < 4; ++i)
#pragma unroll
    for (int j = 0; j < 4; ++j) acc[i][j] = (f32x4){0.f, 0.f, 0.f, 0.f};

  const int brow = lane >> 3;                              // row within 8-row issue
  const int bcol = (((lane & 7) ^ (brow & 7)) & 7) * 8;    // swizzled source col
  const int wm = (wid >> 1) * 64, wn = (wid & 1) * 64;
  const int fr = lane & 15, fg = lane >> 4;
  const int fr7 = fr & 7;

  for (int k0 = 0; k0 < E_; k0 += 64) {
    __syncthreads();
    // ---- stage A, B direct to LDS (linear dest, pre-swizzled src)
#pragma unroll
    for (int q = 0; q < 4; ++q) {
      const int rb = (wid * 4 + q) * 8;
      GLDS16(xb + (size_t)(m0 + rb + brow) * E_ + k0 + bcol, &sA[rb * 64]);
      GLDS16(Wb + (size_t)(n0 + rb + brow) * E_ + k0 + bcol, &sB[rb * 64]);
    }
    __syncthreads();
    // ---- compute: 32 MFMA, swizzled fragment reads
    short8 afr[4][2], bfr[4][2];
#pragma unroll
    for (int i = 0; i < 4; ++i)
#pragma unroll
      for (int kk = 0; kk < 2; ++kk) {
        const int blk = (((kk * 4 + fg) ^ fr7) << 3);
        afr[i][kk] = *(const short8*)&sA[(wm + i * 16 + fr) * 64 + blk];
        bfr[i][kk] = *(const short8*)&sB[(wn + i * 16 + fr) * 64 + blk];
      }
#pragma unroll
    for (int i = 0; i < 4; ++i)
#pragma unroll
      for (int j = 0; j < 4; ++j)
#pragma unroll
        for (int kk = 0; kk < 2; ++kk)
          acc[i][j] = __builtin_amdgcn_mfma_f32_16x16x32_bf16(
              afr[i][kk], bfr[j][kk], acc[i][j], 0, 0, 0);
  }

  const int wsel = n0 >> 10;
  const float* bias = (wsel == 0) ? bq : (wsel == 1) ? bk : bv;
  float br[4];
#pragma unroll
  for (int j = 0; j < 4; ++j)
    br[j] = bias[(n0 & 1023) + wn + j * 16 + fr];

  if (wsel < 2) {
    unsigned short* T = (wsel == 0) ? QTb : KTb;
    const int b = m0 >> 12;
    const int lbase = (m0 & 4095) + wm + (fg << 2);
#pragma unroll
    for (int i = 0; i < 4; ++i)
#pragma unroll
      for (int j = 0; j < 4; ++j) {
        const int n_in = (n0 & 1023) + wn + j * 16 + fr;
        ushort4 v = make_ushort4(f2bf(acc[i][j][0] + br[j]),
                                 f2bf(acc[i][j][1] + br[j]),
                                 f2bf(acc[i][j][2] + br[j]),
                                 f2bf(acc[i][j][3] + br[j]));
        *(ushort4*)&T[((size_t)(b << 10) + n_in) * L_ + lbase + i * 16] = v;
      }
  } else {
#pragma unroll
    for (int i = 0; i < 4; ++i)
#pragma unroll
      for (int j = 0; j < 4; ++j) {
        const int n_in = (n0 & 1023) + wn + j * 16 + fr;
#pragma unroll
        for (int r = 0; r < 4; ++r) {
          const int m = m0 + wm + i * 16 + (fg << 2) + r;
          Vb[(size_t)m * E_ + n_in] = f2bf(acc[i][j][r] + br[j]);
        }
      }
  }
}

// ---------------------------------------------------------------------------
// In-LDS Stockham radix-4 FFT, N=4096, 1024 threads, 6 stages.
// Twiddles w1[st] precomputed by the caller (depend only on tid & stage),
// reused across repeated FFTs. Stage 0 has w = 1 (skipped).
// ---------------------------------------------------------------------------
__device__ __forceinline__ float2 cmulf(float2 a, float2 b) {
  return make_float2(a.x * b.x - a.y * b.y, a.x * b.y + a.y * b.x);
}

__device__ __forceinline__ void fft_tw_init(float2* tw, int tid, float sign) {
  const float TWO_PI = 6.28318530717958647692f;
#pragma unroll
  for (int st = 0; st < 6; ++st) {
    const int Ns = 1 << (2 * st);
    const int r = tid & (Ns - 1);
    float ang = sign * TWO_PI * (float)r / (float)(4 * Ns);
    __sincosf(ang, &tw[st].y, &tw[st].x);
  }
}

__device__ __forceinline__ void fft4096_tw(float2* __restrict__ A,
                                           float2* __restrict__ Bb, int tid,
                                           float sign,
                                           const float2* __restrict__ tw) {
  float2* cur = A;
  float2* nxt = Bb;
#pragma unroll
  for (int st = 0; st < 6; ++st) {
    const int Ns = 1 << (2 * st);
    __syncthreads();
    const int j = tid;
    float2 v0 = cur[j];
    float2 v1 = cur[j + 1024];
    float2 v2 = cur[j + 2048];
    float2 v3 = cur[j + 3072];
    const int r = j & (Ns - 1);
    if (st > 0) {
      float2 w1 = tw[st];
      float2 w2 = cmulf(w1, w1);
      float2 w3 = cmulf(w2, w1);
      v1 = cmulf(v1, w1);
      v2 = cmulf(v2, w2);
      v3 = cmulf(v3, w3);
    }
    float2 t0 = make_float2(v0.x + v2.x, v0.y + v2.y);
    float2 t1 = make_float2(v0.x - v2.x, v0.y - v2.y);
    float2 t2 = make_float2(v1.x + v3.x, v1.y + v3.y);
    float2 t3 = make_float2(v1.x - v3.x, v1.y - v3.y);
    float2 t3i = make_float2(-sign * t3.y, sign * t3.x);
    const int idxD = ((j - r) << 2) + r;
    nxt[idxD]          = make_float2(t0.x + t2.x, t0.y + t2.y);
    nxt[idxD + Ns]     = make_float2(t1.x + t3i.x, t1.y + t3i.y);
    nxt[idxD + 2 * Ns] = make_float2(t0.x - t2.x, t0.y - t2.y);
    nxt[idxD + 3 * Ns] = make_float2(t1.x - t3i.x, t1.y - t3i.y);
    float2* tmp = cur; cur = nxt; nxt = tmp;
  }
  __syncthreads();
}

// ---------------------------------------------------------------------------
// Kernel 2a: per-(b,h,ds) partial cross-spectrum. 8 packed FFTs per block.
// ---------------------------------------------------------------------------
__global__ __launch_bounds__(1024) void corr_fft(
    const unsigned short* __restrict__ QTb,
    const unsigned short* __restrict__ KTb, float2* __restrict__ Spart) {
  __shared__ float2 bufA[L_];      // 32 KB
  __shared__ float2 bufB[L_];      // 32 KB
  __shared__ float2 S[L_ / 2];     // 16 KB (Nyquist packed into S[0].y)

  const int bh = blockIdx.x, ds = blockIdx.y;
  const int b = bh >> 4, h = bh & (H_ - 1);
  const int tid = threadIdx.x;

  float2 tw[6];
  fft_tw_init(tw, tid, -1.0f);

  for (int f = tid; f < L_ / 2; f += 1024) S[f] = make_float2(0.f, 0.f);

  const size_t baseQK = (size_t)(b * E_ + h * D_) * L_;

  for (int dd = 0; dd < 8; ++dd) {
    const int d = ds * 8 + dd;
    __syncthreads();
    const unsigned short* q = QTb + baseQK + (size_t)d * L_;
    const unsigned short* k = KTb + baseQK + (size_t)d * L_;
    ushort4 q4 = *(const ushort4*)(q + tid * 4);
    ushort4 k4 = *(const ushort4*)(k + tid * 4);
    bufA[tid * 4 + 0] = make_float2(bf2f(q4.x), bf2f(k4.x));
    bufA[tid * 4 + 1] = make_float2(bf2f(q4.y), bf2f(k4.y));
    bufA[tid * 4 + 2] = make_float2(bf2f(q4.z), bf2f(k4.z));
    bufA[tid * 4 + 3] = make_float2(bf2f(q4.w), bf2f(k4.w));
    fft4096_tw(bufA, bufB, tid, -1.0f, tw);
    for (int f = tid; f <= L_ / 2; f += 1024) {
      float2 Zf = bufA[f];
      float2 Zc = bufA[(L_ - f) & (L_ - 1)];
      float ax = Zc.x, ay = -Zc.y;
      float qx = 0.5f * (Zf.x + ax), qy = 0.5f * (Zf.y + ay);
      float ux = Zf.x - ax, uy = Zf.y - ay;
      float kx = 0.5f * uy, ky = -0.5f * ux;
      float re = qx * kx + qy * ky;
      float im = qy * kx - qx * ky;
      if (f == 0) S[0].x += re;
      else if (f == L_ / 2) S[0].y += re;
      else { S[f].x += re; S[f].y += im; }
    }
  }
  __syncthreads();
  float2* out = Spart + (size_t)(bh * 8 + ds) * (L_ / 2);
  for (int f = tid; f < L_ / 2; f += 1024) out[f] = S[f];
}

// ---------------------------------------------------------------------------
// Kernel 2b: per-(b,h) reduce partials -> inverse FFT -> softmax -> attn@V.
// ---------------------------------------------------------------------------
__global__ __launch_bounds__(1024) void corr_post(
    const float2* __restrict__ Spart, const unsigned short* __restrict__ Vb,
    float* __restrict__ out_flat) {
  __shared__ float2 bufA[L_];
  __shared__ float2 bufB[L_];
  __shared__ float red[1024];

  const int bh = blockIdx.x;
  const int b = bh >> 4, h = bh & (H_ - 1);
  const int tid = threadIdx.x;

  float2 tw[6];
  fft_tw_init(tw, tid, 1.0f);

  const float2* sp = Spart + (size_t)(bh * 8) * (L_ / 2);
  for (int f = tid; f < L_ / 2; f += 1024) {
    float2 s = make_float2(0.f, 0.f);
#pragma unroll
    for (int ds = 0; ds < 8; ++ds) {
      float2 p = sp[(size_t)ds * (L_ / 2) + f];
      s.x += p.x;
      s.y += p.y;
    }
    if (f == 0) {
      bufA[0] = make_float2(s.x, 0.f);
      bufA[L_ / 2] = make_float2(s.y, 0.f);
    } else {
      bufA[f] = s;
      bufA[L_ - f] = make_float2(s.x, -s.y);
    }
  }
  fft4096_tw(bufA, bufB, tid, 1.0f, tw);

  const float cscale = 1.0f / ((float)L_ * (float)D_);
  float lmax = -3.0e38f;
#pragma unroll
  for (int q = 0; q < 4; ++q) lmax = fmaxf(lmax, bufA[tid + q * 1024].x);
  red[tid] = lmax;
  __syncthreads();
  for (int s = 512; s > 0; s >>= 1) {
    if (tid < s) red[tid] = fmaxf(red[tid], red[tid + s]);
    __syncthreads();
  }
  const float gmax = red[0] * cscale;
  __syncthreads();
  float lsum = 0.f;
#pragma unroll
  for (int q = 0; q < 4; ++q) {
    float w = __expf(bufA[tid + q * 1024].x * cscale - gmax);
    bufA[tid + q * 1024].x = w;
    lsum += w;
  }
  red[tid] = lsum;
  __syncthreads();
  for (int s = 512; s > 0; s >>= 1) {
    if (tid < s) red[tid] += red[tid + s];
    __syncthreads();
  }
  const float inv = 1.0f / red[0];
  __syncthreads();

  const int d = tid & 63, g = tid >> 6;
  const unsigned short* vb = Vb + (size_t)b * L_ * E_ + h * D_ + d;
  float acc = 0.f;
  for (int l = g; l < L_; l += 16)
    acc = fmaf(bufA[l].x, bf2f(vb[(size_t)l * E_]), acc);
  red[tid] = acc;
  __syncthreads();
  if (tid < 64) {
    float t = 0.f;
#pragma unroll
    for (int g2 = 0; g2 < 16; ++g2) t += red[g2 * 64 + tid];
    out_flat[b * E_ + tid * H_ + h] = t * inv;
  }
}

// ---------------------------------------------------------------------------
// Kernel 3: y[b,o] = bo[o] + sum_j flat[b,j] * Wo[o,j]  (128 blocks)
// ---------------------------------------------------------------------------
__global__ __launch_bounds__(256) void final_proj(
    const float* __restrict__ flat, const float* __restrict__ Wo,
    const float* __restrict__ bo, float* __restrict__ y) {
  __shared__ float sf[E_];
  const int b = blockIdx.y;
  const int o0 = blockIdx.x * 64;
  for (int j = threadIdx.x; j < E_; j += 256) sf[j] = flat[b * E_ + j];
  __syncthreads();
  const int oo = threadIdx.x >> 2, part = threadIdx.x & 3;
  const int o = o0 + oo;
  const float4* wr = (const float4*)(Wo + (size_t)o * E_) + part * 64;
  const float4* fr = (const float4*)sf + part * 64;
  float s = 0.f;
#pragma unroll 8
  for (int i = 0; i < 64; ++i) {
    float4 w = wr[i];
    float4 f = fr[i];
    s += w.x * f.x + w.y * f.y + w.z * f.z + w.w * f.w;
  }
  s += __shfl_xor(s, 1);
  s += __shfl_xor(s, 2);
  if (part == 0) y[b * E_ + o] = s + bo[o];
}

// ---------------------------------------------------------------------------
// Kernel 4: broadcast y (B,E) to out (B,L,E).
// ---------------------------------------------------------------------------
__global__ void broadcast_out(const float* __restrict__ y,
                              float4* __restrict__ out4) {
  const size_t total = (size_t)B_ * L_ * (E_ / 4);
  const float4* y4 = (const float4*)y;
  for (size_t i = (size_t)blockIdx.x * blockDim.x + threadIdx.x; i < total;
       i += (size_t)gridDim.x * blockDim.x) {
    size_t e4 = i & (E_ / 4 - 1);
    size_t b = i >> 20;
    out4[i] = y4[b * (E_ / 4) + e4];
  }
}

// ---------------------------------------------------------------------------
extern "C" void kernel_launch(void* const* d_in, const int* in_sizes, int n_in,
                              void* d_out, int out_size, void* d_ws,
                              size_t ws_size, hipStream_t stream) {
  const float* x  = (const float*)d_in[0];
  const float* Wq = (const float*)d_in[1];
  const float* bq = (const float*)d_in[2];
  const float* Wk = (const float*)d_in[3];
  const float* bk = (const float*)d_in[4];
  const float* Wv = (const float*)d_in[5];
  const float* bv = (const float*)d_in[6];
  const float* Wo = (const float*)d_in[7];
  const float* bo = (const float*)d_in[8];

  // ws layout (bytes):
  //   KTb bf16  @ 0          (67108864)
  //   Vb  bf16  @ 67108864   (67108864)
  //   Wb  bf16  @ 134217728  (6291456)
  //   Spart     @ 140509184  (16777216)
  //   flat      @ 157286400  (32768)
  //   y         @ 157319168  (32768)     => ~157.4 MB
  char* w = (char*)d_ws;
  unsigned short* KTb  = (unsigned short*)w;
  unsigned short* Vb   = (unsigned short*)(w + 67108864);
  unsigned short* Wb   = (unsigned short*)(w + 134217728);
  float2* Spart        = (float2*)(w + 140509184);
  float* flat          = (float*)(w + 157286400);
  float* y             = (float*)(w + 157319168);
  // d_out (134.2 MB) doubles as scratch: QTb bf16 [0:67MB), xb bf16 [67:134MB)
  unsigned short* QTb  = (unsigned short*)d_out;
  unsigned short* xb   = (unsigned short*)((char*)d_out + 67108864);

  conv_w<<<dim3(1024, 3), 256, 0, stream>>>(Wq, Wk, Wv, Wb);
  conv_x<<<dim3(2048), 256, 0, stream>>>(x, xb);
  qkv_gemm<<<dim3(24, 256), 256, 0, stream>>>(xb, Wb, bq, bk, bv, QTb, KTb, Vb);
  corr_fft<<<dim3(B_ * H_, 8), 1024, 0, stream>>>(QTb, KTb, Spart);
  corr_post<<<dim3(B_ * H_), 1024, 0, stream>>>(Spart, Vb, flat);
  final_proj<<<dim3(16, B_), 256, 0, stream>>>(flat, Wo, bo, y);
  broadcast_out<<<dim3(2048), 256, 0, stream>>>(y, (float4*)d_out);
}

// Round 8
// 557.956 us; speedup vs baseline: 7.7094x; 1.0574x over previous
//
#include <hip/hip_runtime.h>
#include <hip/hip_bf16.h>
#include <math.h>

// Problem constants (AutoCorrelationAttention): B=8, L=4096, E=1024, H=16, D=64
#define B_ 8
#define L_ 4096
#define E_ 1024
#define H_ 16
#define D_ 64

typedef short short8 __attribute__((ext_vector_type(8)));
typedef float f32x4 __attribute__((ext_vector_type(4)));

__device__ __forceinline__ unsigned short f2bf(float f) {
  unsigned int u = __float_as_uint(f);
  unsigned int r = u + 0x7FFFu + ((u >> 16) & 1u);
  return (unsigned short)(r >> 16);
}
__device__ __forceinline__ float bf2f(unsigned short h) {
  return __uint_as_float(((unsigned int)h) << 16);
}

#define GLDS16(g, l)                                                     \
  __builtin_amdgcn_global_load_lds(                                      \
      (const __attribute__((address_space(1))) void*)(g),                \
      (__attribute__((address_space(3))) void*)(l), 16, 0, 0)

// ---------------------------------------------------------------------------
// Kernel 0a: convert Wq/Wk/Wv to bf16 (rounded), fused [3072][1024] layout.
// ---------------------------------------------------------------------------
__global__ __launch_bounds__(256) void conv_w(
    const float* __restrict__ Wq, const float* __restrict__ Wk,
    const float* __restrict__ Wv, unsigned short* __restrict__ Wb) {
  const int wsel = blockIdx.y;
  const float* W = (wsel == 0) ? Wq : (wsel == 1) ? Wk : Wv;
  size_t i = ((size_t)blockIdx.x * 256 + threadIdx.x) * 4;
  float4 f = *(const float4*)(W + i);
  size_t o = (size_t)wsel * (1024 * 1024) + i;
  *(ushort4*)(Wb + o) =
      make_ushort4(f2bf(f.x), f2bf(f.y), f2bf(f.z), f2bf(f.w));
}

// ---------------------------------------------------------------------------
// Kernel 0b: convert x (fp32) -> xb (bf16, rounded), natural layout.
// ---------------------------------------------------------------------------
__global__ __launch_bounds__(256) void conv_x(const float* __restrict__ x,
                                              unsigned short* __restrict__ xb) {
  const size_t total = (size_t)B_ * L_ * E_ / 8;
  for (size_t i = (size_t)blockIdx.x * blockDim.x + threadIdx.x; i < total;
       i += (size_t)gridDim.x * blockDim.x) {
    float4 a = ((const float4*)x)[i * 2];
    float4 b = ((const float4*)x)[i * 2 + 1];
    short8 v;
    v[0] = (short)f2bf(a.x); v[1] = (short)f2bf(a.y);
    v[2] = (short)f2bf(a.z); v[3] = (short)f2bf(a.w);
    v[4] = (short)f2bf(b.x); v[5] = (short)f2bf(b.y);
    v[6] = (short)f2bf(b.z); v[7] = (short)f2bf(b.w);
    *(short8*)&xb[i * 8] = v;
  }
}

// ---------------------------------------------------------------------------
// Kernel 1: fused QKV projection — 256x256 8-phase bf16 MFMA GEMM (T2+T3+T4+T5)
//   C[32768,3072] = xb @ Wb^T + bias,  BK=64, 16 K-tiles.
// 8 waves (2Mx4N), per-wave 128x64. Per K-tile: 4 phases, each =
//   {12 ds_read_b128, 2 global_load_lds, barrier, lgkmcnt(0), 16 MFMA, barrier}
// Stage schedule (counted vmcnt, never 0 mid-loop):
//   ph0: A-half1(t+1)->buf^1   ph1: B-half1(t+1)->buf^1
//   ph2: A-half0(t+2)->buf     ph3: B-half0(t+2)->buf
//   boundary: vmcnt(4) (last tile: vmcnt(0)).
// A-half h = rows {h*64..h*64+63} U {128+h*64..}, B-half h = U_wc wc*64+h*32+[0,32)
// T2 swizzle: 16B block p = c ^ (row&7); linear LDS dest + pre-swizzled src.
// ---------------------------------------------------------------------------
#define STAGE_A(buf, h, s, t)                                                \
  GLDS16(xb + (size_t)(m0 + (s)*128 + (h)*64 + srow) * E_ + (t)*64 + scol,   \
         &sA[buf][((s)*128 + (h)*64 + wid * 8) * 64])
#define STAGE_B(buf, h, s, t)                                                \
  GLDS16(Wb + (size_t)(n0 + (s)*128 + (h)*32 + brow_i) * E_ + (t)*64 + scol, \
         &sB[buf][((s)*128 + (h)*32 + bw) * 64])

#define PHASE(mh, nh, STAGE)                                                  \
  {                                                                           \
    short8 af[4][2], bfr[2][2];                                               \
    _Pragma("unroll") for (int i = 0; i < 4; ++i)                             \
    _Pragma("unroll") for (int kk = 0; kk < 2; ++kk) {                        \
      const int blk = (((kk * 4 + fg) ^ fr7) << 3);                           \
      af[i][kk] = *(const short8*)                                            \
          &sA[cur][(wr * 128 + ((mh)*4 + i) * 16 + fr) * 64 + blk];           \
    }                                                                         \
    _Pragma("unroll") for (int j = 0; j < 2; ++j)                             \
    _Pragma("unroll") for (int kk = 0; kk < 2; ++kk) {                        \
      const int blk = (((kk * 4 + fg) ^ fr7) << 3);                           \
      bfr[j][kk] = *(const short8*)                                           \
          &sB[cur][(wc * 64 + ((nh)*2 + j) * 16 + fr) * 64 + blk];            \
    }                                                                         \
    STAGE;                                                                    \
    __builtin_amdgcn_s_barrier();                                             \
    asm volatile("s_waitcnt lgkmcnt(0)" ::: "memory");                        \
    __builtin_amdgcn_sched_barrier(0);                                        \
    __builtin_amdgcn_s_setprio(1);                                            \
    _Pragma("unroll") for (int i = 0; i < 4; ++i)                             \
    _Pragma("unroll") for (int j = 0; j < 2; ++j)                             \
    _Pragma("unroll") for (int kk = 0; kk < 2; ++kk)                          \
      acc[(mh)*4 + i][(nh)*2 + j] = __builtin_amdgcn_mfma_f32_16x16x32_bf16(  \
          af[i][kk], bfr[j][kk], acc[(mh)*4 + i][(nh)*2 + j], 0, 0, 0);       \
    __builtin_amdgcn_s_setprio(0);                                            \
    __builtin_amdgcn_s_barrier();                                             \
  }

__global__ __launch_bounds__(512) void qkv_gemm8(
    const unsigned short* __restrict__ xb,
    const unsigned short* __restrict__ Wb, const float* __restrict__ bq,
    const float* __restrict__ bk, const float* __restrict__ bv,
    unsigned short* __restrict__ QTb, unsigned short* __restrict__ KTb,
    unsigned short* __restrict__ Vb) {
  __shared__ unsigned short sA[2][256 * 64];  // 2 x 32 KB
  __shared__ unsigned short sB[2][256 * 64];  // 2 x 32 KB

  const int tid = threadIdx.x;
  const int wid = tid >> 6, lane = tid & 63;
  const int wr = wid >> 2, wc = wid & 3;
  const int fr = lane & 15, fg = lane >> 4, fr7 = fr & 7;
  const int n0 = blockIdx.x * 256;
  const int m0 = blockIdx.y * 256;

  // staging maps
  const int srow = tid >> 3;                              // 0..63
  const int scol = ((tid & 7) ^ (srow & 7)) * 8;          // pre-swizzled col
  const int brow_i = ((srow >> 5) << 6) + (srow & 31);    // B interleaved row
  const int bw = ((wid >> 2) << 6) + ((wid & 3) << 3);    // B wave dest row

  f32x4 acc[8][4];
#pragma unroll
  for (int i = 0; i < 8; ++i)
#pragma unroll
    for (int j = 0; j < 4; ++j) acc[i][j] = (f32x4){0.f, 0.f, 0.f, 0.f};

  // prologue: tile0 {A0,B0,A1,B1}, tile1 {A0,B0}  (12 loads/thread)
  STAGE_A(0, 0, 0, 0); STAGE_A(0, 0, 1, 0);
  STAGE_B(0, 0, 0, 0); STAGE_B(0, 0, 1, 0);
  STAGE_A(0, 1, 0, 0); STAGE_A(0, 1, 1, 0);
  STAGE_B(0, 1, 0, 0); STAGE_B(0, 1, 1, 0);
  STAGE_A(1, 0, 0, 1); STAGE_A(1, 0, 1, 1);
  STAGE_B(1, 0, 0, 1); STAGE_B(1, 0, 1, 1);

  const int NT = E_ / 64;  // 16 K-tiles
  for (int u = 0; u < NT; ++u) {
    const int cur = u & 1, nxt = cur ^ 1;
    __builtin_amdgcn_sched_barrier(0);
    if (u == NT - 1)
      asm volatile("s_waitcnt vmcnt(0)" ::: "memory");
    else
      asm volatile("s_waitcnt vmcnt(4)" ::: "memory");
    __builtin_amdgcn_sched_barrier(0);
    __builtin_amdgcn_s_barrier();
    PHASE(0, 0, if (u + 1 < NT) { STAGE_A(nxt, 1, 0, u + 1); STAGE_A(nxt, 1, 1, u + 1); })
    PHASE(0, 1, if (u + 1 < NT) { STAGE_B(nxt, 1, 0, u + 1); STAGE_B(nxt, 1, 1, u + 1); })
    PHASE(1, 0, if (u + 2 < NT) { STAGE_A(cur, 0, 0, u + 2); STAGE_A(cur, 0, 1, u + 2); })
    PHASE(1, 1, if (u + 2 < NT) { STAGE_B(cur, 0, 0, u + 2); STAGE_B(cur, 0, 1, u + 2); })
  }

  // ---- epilogue
  const int wsel = n0 >> 10;
  const float* bias = (wsel == 0) ? bq : (wsel == 1) ? bk : bv;
  float br[4];
#pragma unroll
  for (int j = 0; j < 4; ++j)
    br[j] = bias[(n0 & 1023) + wc * 64 + j * 16 + fr];

  if (wsel < 2) {
    unsigned short* T = (wsel == 0) ? QTb : KTb;
    const int b = m0 >> 12;
    const int lbase = (m0 & 4095) + wr * 128 + (fg << 2);
#pragma unroll
    for (int i = 0; i < 8; ++i)
#pragma unroll
      for (int j = 0; j < 4; ++j) {
        const int n_in = (n0 & 1023) + wc * 64 + j * 16 + fr;
        ushort4 v = make_ushort4(f2bf(acc[i][j][0] + br[j]),
                                 f2bf(acc[i][j][1] + br[j]),
                                 f2bf(acc[i][j][2] + br[j]),
                                 f2bf(acc[i][j][3] + br[j]));
        *(ushort4*)&T[((size_t)(b << 10) + n_in) * L_ + lbase + i * 16] = v;
      }
  } else {
#pragma unroll
    for (int i = 0; i < 8; ++i)
#pragma unroll
      for (int j = 0; j < 4; ++j) {
        const int n_in = (n0 & 1023) + wc * 64 + j * 16 + fr;
#pragma unroll
        for (int r = 0; r < 4; ++r) {
          const int m = m0 + wr * 128 + i * 16 + (fg << 2) + r;
          Vb[(size_t)m * E_ + n_in] = f2bf(acc[i][j][r] + br[j]);
        }
      }
  }
}

// ---------------------------------------------------------------------------
// In-LDS Stockham radix-4 FFT, N=4096, 1024 threads, 6 stages.
// Twiddles precomputed per caller (depend only on tid & stage).
// ---------------------------------------------------------------------------
__device__ __forceinline__ float2 cmulf(float2 a, float2 b) {
  return make_float2(a.x * b.x - a.y * b.y, a.x * b.y + a.y * b.x);
}

__device__ __forceinline__ void fft_tw_init(float2* tw, int tid, float sign) {
  const float TWO_PI = 6.28318530717958647692f;
#pragma unroll
  for (int st = 0; st < 6; ++st) {
    const int Ns = 1 << (2 * st);
    const int r = tid & (Ns - 1);
    float ang = sign * TWO_PI * (float)r / (float)(4 * Ns);
    __sincosf(ang, &tw[st].y, &tw[st].x);
  }
}

__device__ __forceinline__ void fft4096_tw(float2* __restrict__ A,
                                           float2* __restrict__ Bb, int tid,
                                           float sign,
                                           const float2* __restrict__ tw) {
  float2* cur = A;
  float2* nxt = Bb;
#pragma unroll
  for (int st = 0; st < 6; ++st) {
    const int Ns = 1 << (2 * st);
    __syncthreads();
    const int j = tid;
    float2 v0 = cur[j];
    float2 v1 = cur[j + 1024];
    float2 v2 = cur[j + 2048];
    float2 v3 = cur[j + 3072];
    const int r = j & (Ns - 1);
    if (st > 0) {
      float2 w1 = tw[st];
      float2 w2 = cmulf(w1, w1);
      float2 w3 = cmulf(w2, w1);
      v1 = cmulf(v1, w1);
      v2 = cmulf(v2, w2);
      v3 = cmulf(v3, w3);
    }
    float2 t0 = make_float2(v0.x + v2.x, v0.y + v2.y);
    float2 t1 = make_float2(v0.x - v2.x, v0.y - v2.y);
    float2 t2 = make_float2(v1.x + v3.x, v1.y + v3.y);
    float2 t3 = make_float2(v1.x - v3.x, v1.y - v3.y);
    float2 t3i = make_float2(-sign * t3.y, sign * t3.x);
    const int idxD = ((j - r) << 2) + r;
    nxt[idxD]          = make_float2(t0.x + t2.x, t0.y + t2.y);
    nxt[idxD + Ns]     = make_float2(t1.x + t3i.x, t1.y + t3i.y);
    nxt[idxD + 2 * Ns] = make_float2(t0.x - t2.x, t0.y - t2.y);
    nxt[idxD + 3 * Ns] = make_float2(t1.x - t3i.x, t1.y - t3i.y);
    float2* tmp = cur; cur = nxt; nxt = tmp;
  }
  __syncthreads();
}

// ---------------------------------------------------------------------------
// Kernel 2a: per-(b,h,ds) partial cross-spectrum. 8 packed FFTs per block.
// ---------------------------------------------------------------------------
__global__ __launch_bounds__(1024) void corr_fft(
    const unsigned short* __restrict__ QTb,
    const unsigned short* __restrict__ KTb, float2* __restrict__ Spart) {
  __shared__ float2 bufA[L_];      // 32 KB
  __shared__ float2 bufB[L_];      // 32 KB
  __shared__ float2 S[L_ / 2];     // 16 KB (Nyquist packed into S[0].y)

  const int bh = blockIdx.x, ds = blockIdx.y;
  const int b = bh >> 4, h = bh & (H_ - 1);
  const int tid = threadIdx.x;

  float2 tw[6];
  fft_tw_init(tw, tid, -1.0f);

  for (int f = tid; f < L_ / 2; f += 1024) S[f] = make_float2(0.f, 0.f);

  const size_t baseQK = (size_t)(b * E_ + h * D_) * L_;

  for (int dd = 0; dd < 8; ++dd) {
    const int d = ds * 8 + dd;
    __syncthreads();
    const unsigned short* q = QTb + baseQK + (size_t)d * L_;
    const unsigned short* k = KTb + baseQK + (size_t)d * L_;
    ushort4 q4 = *(const ushort4*)(q + tid * 4);
    ushort4 k4 = *(const ushort4*)(k + tid * 4);
    bufA[tid * 4 + 0] = make_float2(bf2f(q4.x), bf2f(k4.x));
    bufA[tid * 4 + 1] = make_float2(bf2f(q4.y), bf2f(k4.y));
    bufA[tid * 4 + 2] = make_float2(bf2f(q4.z), bf2f(k4.z));
    bufA[tid * 4 + 3] = make_float2(bf2f(q4.w), bf2f(k4.w));
    fft4096_tw(bufA, bufB, tid, -1.0f, tw);
    for (int f = tid; f <= L_ / 2; f += 1024) {
      float2 Zf = bufA[f];
      float2 Zc = bufA[(L_ - f) & (L_ - 1)];
      float ax = Zc.x, ay = -Zc.y;
      float qx = 0.5f * (Zf.x + ax), qy = 0.5f * (Zf.y + ay);
      float ux = Zf.x - ax, uy = Zf.y - ay;
      float kx = 0.5f * uy, ky = -0.5f * ux;
      float re = qx * kx + qy * ky;
      float im = qy * kx - qx * ky;
      if (f == 0) S[0].x += re;
      else if (f == L_ / 2) S[0].y += re;
      else { S[f].x += re; S[f].y += im; }
    }
  }
  __syncthreads();
  float2* out = Spart + (size_t)(bh * 8 + ds) * (L_ / 2);
  for (int f = tid; f < L_ / 2; f += 1024) out[f] = S[f];
}

// ---------------------------------------------------------------------------
// Kernel 2b: per-(b,h) reduce partials -> inverse FFT -> softmax -> attn@V.
// ---------------------------------------------------------------------------
__global__ __launch_bounds__(1024) void corr_post(
    const float2* __restrict__ Spart, const unsigned short* __restrict__ Vb,
    float* __restrict__ out_flat) {
  __shared__ float2 bufA[L_];
  __shared__ float2 bufB[L_];
  __shared__ float red[1024];

  const int bh = blockIdx.x;
  const int b = bh >> 4, h = bh & (H_ - 1);
  const int tid = threadIdx.x;

  float2 tw[6];
  fft_tw_init(tw, tid, 1.0f);

  const float2* sp = Spart + (size_t)(bh * 8) * (L_ / 2);
  for (int f = tid; f < L_ / 2; f += 1024) {
    float2 s = make_float2(0.f, 0.f);
#pragma unroll
    for (int ds = 0; ds < 8; ++ds) {
      float2 p = sp[(size_t)ds * (L_ / 2) + f];
      s.x += p.x;
      s.y += p.y;
    }
    if (f == 0) {
      bufA[0] = make_float2(s.x, 0.f);
      bufA[L_ / 2] = make_float2(s.y, 0.f);
    } else {
      bufA[f] = s;
      bufA[L_ - f] = make_float2(s.x, -s.y);
    }
  }
  fft4096_tw(bufA, bufB, tid, 1.0f, tw);

  const float cscale = 1.0f / ((float)L_ * (float)D_);
  float lmax = -3.0e38f;
#pragma unroll
  for (int q = 0; q < 4; ++q) lmax = fmaxf(lmax, bufA[tid + q * 1024].x);
  red[tid] = lmax;
  __syncthreads();
  for (int s = 512; s > 0; s >>= 1) {
    if (tid < s) red[tid] = fmaxf(red[tid], red[tid + s]);
    __syncthreads();
  }
  const float gmax = red[0] * cscale;
  __syncthreads();
  float lsum = 0.f;
#pragma unroll
  for (int q = 0; q < 4; ++q) {
    float w = __expf(bufA[tid + q * 1024].x * cscale - gmax);
    bufA[tid + q * 1024].x = w;
    lsum += w;
  }
  red[tid] = lsum;
  __syncthreads();
  for (int s = 512; s > 0; s >>= 1) {
    if (tid < s) red[tid] += red[tid + s];
    __syncthreads();
  }
  const float inv = 1.0f / red[0];
  __syncthreads();

  const int d = tid & 63, g = tid >> 6;
  const unsigned short* vb = Vb + (size_t)b * L_ * E_ + h * D_ + d;
  float acc = 0.f;
  for (int l = g; l < L_; l += 16)
    acc = fmaf(bufA[l].x, bf2f(vb[(size_t)l * E_]), acc);
  red[tid] = acc;
  __syncthreads();
  if (tid < 64) {
    float t = 0.f;
#pragma unroll
    for (int g2 = 0; g2 < 16; ++g2) t += red[g2 * 64 + tid];
    out_flat[b * E_ + tid * H_ + h] = t * inv;
  }
}

// ---------------------------------------------------------------------------
// Kernel 3: y[b,o] = bo[o] + sum_j flat[b,j] * Wo[o,j]  (128 blocks)
// ---------------------------------------------------------------------------
__global__ __launch_bounds__(256) void final_proj(
    const float* __restrict__ flat, const float* __restrict__ Wo,
    const float* __restrict__ bo, float* __restrict__ y) {
  __shared__ float sf[E_];
  const int b = blockIdx.y;
  const int o0 = blockIdx.x * 64;
  for (int j = threadIdx.x; j < E_; j += 256) sf[j] = flat[b * E_ + j];
  __syncthreads();
  const int oo = threadIdx.x >> 2, part = threadIdx.x & 3;
  const int o = o0 + oo;
  const float4* wr = (const float4*)(Wo + (size_t)o * E_) + part * 64;
  const float4* fr = (const float4*)sf + part * 64;
  float s = 0.f;
#pragma unroll 8
  for (int i = 0; i < 64; ++i) {
    float4 w = wr[i];
    float4 f = fr[i];
    s += w.x * f.x + w.y * f.y + w.z * f.z + w.w * f.w;
  }
  s += __shfl_xor(s, 1);
  s += __shfl_xor(s, 2);
  if (part == 0) y[b * E_ + o] = s + bo[o];
}

// ---------------------------------------------------------------------------
// Kernel 4: broadcast y (B,E) to out (B,L,E).
// ---------------------------------------------------------------------------
__global__ void broadcast_out(const float* __restrict__ y,
                              float4* __restrict__ out4) {
  const size_t total = (size_t)B_ * L_ * (E_ / 4);
  const float4* y4 = (const float4*)y;
  for (size_t i = (size_t)blockIdx.x * blockDim.x + threadIdx.x; i < total;
       i += (size_t)gridDim.x * blockDim.x) {
    size_t e4 = i & (E_ / 4 - 1);
    size_t b = i >> 20;
    out4[i] = y4[b * (E_ / 4) + e4];
  }
}

// ---------------------------------------------------------------------------
extern "C" void kernel_launch(void* const* d_in, const int* in_sizes, int n_in,
                              void* d_out, int out_size, void* d_ws,
                              size_t ws_size, hipStream_t stream) {
  const float* x  = (const float*)d_in[0];
  const float* Wq = (const float*)d_in[1];
  const float* bq = (const float*)d_in[2];
  const float* Wk = (const float*)d_in[3];
  const float* bk = (const float*)d_in[4];
  const float* Wv = (const float*)d_in[5];
  const float* bv = (const float*)d_in[6];
  const float* Wo = (const float*)d_in[7];
  const float* bo = (const float*)d_in[8];

  // ws layout (bytes):
  //   KTb bf16  @ 0          (67108864)
  //   Vb  bf16  @ 67108864   (67108864)
  //   Wb  bf16  @ 134217728  (6291456)
  //   Spart     @ 140509184  (16777216)
  //   flat      @ 157286400  (32768)
  //   y         @ 157319168  (32768)     => ~157.4 MB
  char* w = (char*)d_ws;
  unsigned short* KTb  = (unsigned short*)w;
  unsigned short* Vb   = (unsigned short*)(w + 67108864);
  unsigned short* Wb   = (unsigned short*)(w + 134217728);
  float2* Spart        = (float2*)(w + 140509184);
  float* flat          = (float*)(w + 157286400);
  float* y             = (float*)(w + 157319168);
  // d_out (134.2 MB) doubles as scratch: QTb bf16 [0:67MB), xb bf16 [67:134MB)
  unsigned short* QTb  = (unsigned short*)d_out;
  unsigned short* xb   = (unsigned short*)((char*)d_out + 67108864);

  conv_w<<<dim3(1024, 3), 256, 0, stream>>>(Wq, Wk, Wv, Wb);
  conv_x<<<dim3(2048), 256, 0, stream>>>(x, xb);
  qkv_gemm8<<<dim3(12, 128), 512, 0, stream>>>(xb, Wb, bq, bk, bv, QTb, KTb,
                                               Vb);
  corr_fft<<<dim3(B_ * H_, 8), 1024, 0, stream>>>(QTb, KTb, Spart);
  corr_post<<<dim3(B_ * H_), 1024, 0, stream>>>(Spart, Vb, flat);
  final_proj<<<dim3(16, B_), 256, 0, stream>>>(flat, Wo, bo, y);
  broadcast_out<<<dim3(2048), 256, 0, stream>>>(y, (float4*)d_out);
}